// Round 1
// baseline (29099.893 us; speedup 1.0000x reference)
//
#include <hip/hip_runtime.h>
#include <math.h>

#define LAYERS 12
#define DMODEL 768
#define NHEAD 12
#define DHEAD 64
#define DFF 3072
#define BATCH 8
#define SEQ 512
#define NTOK (BATCH*SEQ)   /* 4096 */
#define KLEN 1024
#define SCALE 0.125f       /* 1/sqrt(64) */

// ---------------- embedding gather: h[i*B+b][d] = emb[tox[b][i]][d] ----------------
__global__ void k_embed(const int* __restrict__ tox, const float* __restrict__ emb,
                        float* __restrict__ h) {
  int n = blockIdx.x;            // n = i*BATCH + b
  int i = n >> 3, b = n & 7;
  int tok = tox[b*SEQ + i];
  const float* src = emb + (size_t)tok * DMODEL;
  float* dst = h + (size_t)n * DMODEL;
  for (int d = threadIdx.x; d < DMODEL; d += blockDim.x) dst[d] = src[d];
}

// ---------------- positional encoding r[k][d], k in [0,1024) ----------------
__global__ void k_posenc(float* __restrict__ r) {
  int idx = blockIdx.x * blockDim.x + threadIdx.x;
  if (idx >= KLEN * DMODEL) return;
  int k = idx / DMODEL, d = idx % DMODEL;
  float pos = (float)(SEQ - k);                  // 512 - k
  int j = (d < 384) ? d : d - 384;
  float invf = powf(10000.0f, -(2.0f * (float)j) / 768.0f);
  float a = pos * invf;
  r[idx] = (d < 384) ? sinf(a) : cosf(a);
}

// ---------------- GEMM: C[M,N] = A[M,K] @ W (+bias, act) ----------------
// BT=0: W is K x N row-major.  BT=1: W is N x K row-major (C = A @ W^T).
// ACT: 0 none, 1 exact GELU, 2 tanh
template<int BT, int ACT>
__global__ __launch_bounds__(256) void k_gemm(
    const float* __restrict__ A, const float* __restrict__ W,
    const float* __restrict__ bias, float* __restrict__ C,
    int M, int N, int K) {
  const int BM = 128, BN = 64, BK = 16;
  __shared__ float As[BK][BM+4];   // pad -> 132 (16B-aligned rows, conflict-free)
  __shared__ float Ws[BK][BN+4];   // pad -> 68
  int tid = threadIdx.x;
  int tx = tid & 15, ty = tid >> 4;
  int m0 = blockIdx.y * BM, n0 = blockIdx.x * BN;
  float acc[8][4];
  #pragma unroll
  for (int i = 0; i < 8; ++i)
    #pragma unroll
    for (int j = 0; j < 4; ++j) acc[i][j] = 0.f;

  for (int k0 = 0; k0 < K; k0 += BK) {   // K is always a multiple of 16
    {
      int c = tid & 15, r0 = tid >> 4;
      #pragma unroll
      for (int p = 0; p < 8; ++p) {
        int rr = r0 + p*16;
        int gm = m0 + rr;
        As[c][rr] = (gm < M) ? A[(size_t)gm*K + (k0 + c)] : 0.f;
      }
    }
    if (BT == 0) {
      int c = tid & 63, r0 = tid >> 6;
      #pragma unroll
      for (int p = 0; p < 4; ++p) {
        int rr = r0 + p*4;
        int gn = n0 + c;
        Ws[rr][c] = (gn < N) ? W[(size_t)(k0+rr)*N + gn] : 0.f;
      }
    } else {
      int c = tid & 15, r0 = tid >> 4;
      #pragma unroll
      for (int p = 0; p < 4; ++p) {
        int rr = r0 + p*16;
        int gn = n0 + rr;
        Ws[c][rr] = (gn < N) ? W[(size_t)gn*K + (k0+c)] : 0.f;
      }
    }
    __syncthreads();
    #pragma unroll
    for (int k = 0; k < BK; ++k) {
      float a[8], b[4];
      #pragma unroll
      for (int i = 0; i < 8; ++i) a[i] = As[k][ty*8+i];
      #pragma unroll
      for (int j = 0; j < 4; ++j) b[j] = Ws[k][tx*4+j];
      #pragma unroll
      for (int i = 0; i < 8; ++i)
        #pragma unroll
        for (int j = 0; j < 4; ++j) acc[i][j] += a[i]*b[j];
    }
    __syncthreads();
  }
  #pragma unroll
  for (int i = 0; i < 8; ++i) {
    int gm = m0 + ty*8 + i;
    if (gm >= M) continue;
    #pragma unroll
    for (int j = 0; j < 4; ++j) {
      int gn = n0 + tx*4 + j;
      if (gn >= N) continue;
      float v = acc[i][j];
      if (bias) v += bias[gn];
      if (ACT == 1) v = 0.5f*v*(1.0f + erff(v*0.70710678118654752f));
      else if (ACT == 2) v = tanhf(v);
      C[(size_t)gm*N + gn] = v;
    }
  }
}

// ---------------- relative attention, flash-style, one thread per query row ----------------
// score[i,j] = ( q_i·kh_j + rwb·kh_j  +  q_i·kr_{j+512-i} + rrb·kr_{j+512-i} ) * SCALE
#define ATI 128
#define ATJ 32
#define KRROWS (ATJ + ATI - 1)   /* 159 */

__global__ __launch_bounds__(128) void k_attn(
    const float* __restrict__ qh, const float* __restrict__ kh,
    const float* __restrict__ vh, const float* __restrict__ kr,
    const float* __restrict__ rwb, const float* __restrict__ rrb,
    float* __restrict__ vec) {
  int bid = blockIdx.x;
  int it = bid & 3;
  int bn = bid >> 2;
  int n = bn % NHEAD, b = bn / NHEAD;
  int i0 = it * ATI;
  int li = threadIdx.x;            // 0..127
  int i = i0 + li;                 // this thread's query row

  __shared__ float kh_s[ATJ][64];          // 8 KB
  __shared__ float vh_s[ATJ][64];          // 8 KB
  __shared__ float kr_s[KRROWS*65];        // 41.3 KB (pad 65: conflict-free per-lane rows)
  __shared__ float ck_s[ATJ];
  __shared__ float cr_s[KRROWS];
  __shared__ float rwb_s[64], rrb_s[64];

  if (li < 64) rwb_s[li] = rwb[n*64 + li];
  else         rrb_s[li-64] = rrb[n*64 + (li-64)];

  float q[64];
  {
    const float* qp = qh + (size_t)(i*BATCH + b)*DMODEL + n*64;
    #pragma unroll
    for (int d = 0; d < 64; ++d) q[d] = qp[d];
  }
  float acc[64];
  #pragma unroll
  for (int d = 0; d < 64; ++d) acc[d] = 0.f;
  float m = -1e30f, ssum = 0.f;

  __syncthreads();

  #pragma unroll 1
  for (int jt = 0; jt < SEQ/ATJ; ++jt) {
    int j0 = jt * ATJ;
    int kmin = j0 + SEQ - i0 - (ATI - 1);   // lowest kr row needed; always in [1,1023-158]
    // stage kh/vh tiles (32 x 64 each)
    #pragma unroll
    for (int p = 0; p < 16; ++p) {
      int idx = li + p*128;
      int rr = idx >> 6, d = idx & 63;
      int j = j0 + rr;
      kh_s[rr][d] = kh[(size_t)(j*BATCH + b)*DMODEL + n*64 + d];
      vh_s[rr][d] = vh[(size_t)(j*BATCH + b)*DMODEL + n*64 + d];
    }
    // stage kr sliding window (159 x 64)
    for (int idx = li; idx < KRROWS*64; idx += 128) {
      int rr = idx >> 6, d = idx & 63;
      kr_s[rr*65 + d] = kr[(size_t)(kmin + rr)*DMODEL + n*64 + d];
    }
    __syncthreads();
    // i-independent bias dot-products
    if (li < ATJ) {
      float s = 0.f;
      #pragma unroll
      for (int d = 0; d < 64; ++d) s += rwb_s[d]*kh_s[li][d];
      ck_s[li] = s;
    }
    for (int rr = li; rr < KRROWS; rr += 128) {
      float s = 0.f;
      #pragma unroll
      for (int d = 0; d < 64; ++d) s += rrb_s[d]*kr_s[rr*65 + d];
      cr_s[rr] = s;
    }
    __syncthreads();
    #pragma unroll 1
    for (int jj = 0; jj < ATJ; ++jj) {
      const float* khp = kh_s[jj];
      int krow = jj + (ATI-1) - li;          // in [0,158]
      const float* krp = &kr_s[krow*65];
      float s0=0.f, s1=0.f, s2=0.f, s3=0.f;
      #pragma unroll
      for (int d = 0; d < 64; d += 4) {
        s0 += q[d+0]*(khp[d+0]+krp[d+0]);
        s1 += q[d+1]*(khp[d+1]+krp[d+1]);
        s2 += q[d+2]*(khp[d+2]+krp[d+2]);
        s3 += q[d+3]*(khp[d+3]+krp[d+3]);
      }
      float s = (((s0+s1)+(s2+s3)) + ck_s[jj] + cr_s[krow]) * SCALE;
      if (s > m) {                            // online-softmax rescale
        float f = __expf(m - s);
        ssum *= f;
        #pragma unroll
        for (int d = 0; d < 64; ++d) acc[d] *= f;
        m = s;
      }
      float p = __expf(s - m);
      ssum += p;
      const float* vp = vh_s[jj];
      #pragma unroll
      for (int d = 0; d < 64; ++d) acc[d] += p*vp[d];
    }
    __syncthreads();
  }
  float inv = 1.0f/ssum;
  float* op = vec + (size_t)(i*BATCH + b)*DMODEL + n*64;
  #pragma unroll
  for (int d = 0; d < 64; ++d) op[d] = acc[d]*inv;
}

// ---------------- LayerNorm(x + res) -> out (two-pass, per-row block) ----------------
__global__ __launch_bounds__(256) void k_ln_res(
    const float* __restrict__ x, const float* __restrict__ res,
    const float* __restrict__ g, const float* __restrict__ bta,
    float* __restrict__ out) {
  __shared__ float red[4];
  int row = blockIdx.x;
  size_t off = (size_t)row * DMODEL;
  int tid = threadIdx.x;
  float loc[3];
  float s = 0.f;
  #pragma unroll
  for (int p = 0; p < 3; ++p) {
    int d = tid + p*256;
    float v = x[off+d] + res[off+d];
    loc[p] = v; s += v;
  }
  #pragma unroll
  for (int o = 32; o; o >>= 1) s += __shfl_down(s, o, 64);
  if ((tid & 63) == 0) red[tid >> 6] = s;
  __syncthreads();
  float mean = (red[0]+red[1]+red[2]+red[3]) * (1.0f/DMODEL);
  __syncthreads();
  float vs = 0.f;
  #pragma unroll
  for (int p = 0; p < 3; ++p) { float d2 = loc[p] - mean; vs += d2*d2; }
  #pragma unroll
  for (int o = 32; o; o >>= 1) vs += __shfl_down(vs, o, 64);
  if ((tid & 63) == 0) red[tid >> 6] = vs;
  __syncthreads();
  float var = (red[0]+red[1]+red[2]+red[3]) * (1.0f/DMODEL);
  float rstd = 1.0f / sqrtf(var + 1e-12f);
  #pragma unroll
  for (int p = 0; p < 3; ++p) {
    int d = tid + p*256;
    out[off+d] = (loc[p]-mean)*rstd*g[d] + bta[d];
  }
}

extern "C" void kernel_launch(void* const* d_in, const int* in_sizes, int n_in,
                              void* d_out, int out_size, void* d_ws, size_t ws_size,
                              hipStream_t stream) {
  (void)in_sizes; (void)n_in; (void)out_size; (void)ws_size;
  const int*   tox  = (const int*)d_in[0];
  // d_in[1] = ntox (unused), d_in[2] = attn_mask (all-ones -> mask term is exactly 0)
  const float* emb  = (const float*)d_in[3];
  const float* q_w  = (const float*)d_in[4];
  const float* k_w  = (const float*)d_in[5];
  const float* v_w  = (const float*)d_in[6];
  const float* o_w  = (const float*)d_in[7];
  const float* r_w  = (const float*)d_in[8];
  const float* rwb  = (const float*)d_in[9];
  const float* rrb  = (const float*)d_in[10];
  const float* ln1g = (const float*)d_in[11];
  const float* ln1b = (const float*)d_in[12];
  const float* fw1  = (const float*)d_in[13];
  const float* fb1  = (const float*)d_in[14];
  const float* fw2  = (const float*)d_in[15];
  const float* fb2  = (const float*)d_in[16];
  const float* ln2g = (const float*)d_in[17];
  const float* ln2b = (const float*)d_in[18];
  const float* sumw = (const float*)d_in[19];
  const float* sumb = (const float*)d_in[20];
  const float* pjw  = (const float*)d_in[21];
  const float* pjb  = (const float*)d_in[22];
  float* out = (float*)d_out;

  // workspace layout (floats); total ~20.45M floats = 78 MB
  float* ws = (float*)d_ws;
  float* r    = ws;
  float* h    = r   + (size_t)KLEN*DMODEL;
  float* A1   = h   + (size_t)NTOK*DMODEL;
  float* A2   = A1  + (size_t)NTOK*DMODEL;
  float* A3   = A2  + (size_t)NTOK*DMODEL;
  float* A4   = A3  + (size_t)NTOK*DMODEL;
  float* A5   = A4  + (size_t)NTOK*DMODEL;
  float* krb  = A5  + (size_t)NTOK*DMODEL;
  float* summ = krb + (size_t)KLEN*DMODEL;
  float* mid  = A1;   // FF intermediate 4096x3072 aliases A1..A4 (dead during FF)

  dim3 b256(256);
  k_embed<<<NTOK, b256, 0, stream>>>(tox, emb, h);
  k_posenc<<<(KLEN*DMODEL + 255)/256, b256, 0, stream>>>(r);

  dim3 g768(DMODEL/64, NTOK/128);   // (12, 32)
  dim3 gkr (DMODEL/64, KLEN/128);   // (12, 8)
  dim3 gff1(DFF/64,    NTOK/128);   // (48, 32)

  for (int l = 0; l < LAYERS; ++l) {
    const float* qw = q_w + (size_t)l*DMODEL*DMODEL;
    const float* kw = k_w + (size_t)l*DMODEL*DMODEL;
    const float* vw = v_w + (size_t)l*DMODEL*DMODEL;
    const float* ow = o_w + (size_t)l*DMODEL*DMODEL;
    const float* rw = r_w + (size_t)l*DMODEL*DMODEL;
    const float* w1 = fw1 + (size_t)l*DMODEL*DFF;
    const float* w2 = fw2 + (size_t)l*DFF*DMODEL;

    k_gemm<0,0><<<g768, b256, 0, stream>>>(h, qw, nullptr, A1, NTOK, DMODEL, DMODEL);
    k_gemm<0,0><<<g768, b256, 0, stream>>>(h, kw, nullptr, A2, NTOK, DMODEL, DMODEL);
    k_gemm<0,0><<<g768, b256, 0, stream>>>(h, vw, nullptr, A3, NTOK, DMODEL, DMODEL);
    k_gemm<0,0><<<gkr,  b256, 0, stream>>>(r, rw, nullptr, krb, KLEN, DMODEL, DMODEL);

    k_attn<<<BATCH*NHEAD*4, dim3(128), 0, stream>>>(A1, A2, A3, krb,
                                                    rwb + l*DMODEL, rrb + l*DMODEL, A4);

    k_gemm<1,0><<<g768, b256, 0, stream>>>(A4, ow, nullptr, A5, NTOK, DMODEL, DMODEL);
    k_ln_res<<<NTOK, b256, 0, stream>>>(A5, h, ln1g + l*DMODEL, ln1b + l*DMODEL, h);

    k_gemm<0,1><<<gff1, b256, 0, stream>>>(h, w1, fb1 + (size_t)l*DFF, mid, NTOK, DFF, DMODEL);
    k_gemm<0,0><<<g768, b256, 0, stream>>>(mid, w2, fb2 + l*DMODEL, A5, NTOK, DMODEL, DFF);
    k_ln_res<<<NTOK, b256, 0, stream>>>(A5, h, ln2g + l*DMODEL, ln2b + l*DMODEL, h);
  }

  // head: last token rows are the final BATCH rows of h (i=511, b=0..7)
  const float* lastp = h + (size_t)(NTOK - BATCH)*DMODEL;
  k_gemm<0,2><<<dim3(DMODEL/64, 1), b256, 0, stream>>>(lastp, sumw, sumb, summ, BATCH, DMODEL, DMODEL);
  k_gemm<0,0><<<dim3(1, 1), b256, 0, stream>>>(summ, pjw, pjb, out, BATCH, 2, DMODEL);
}

// Round 2
// 9203.312 us; speedup vs baseline: 3.1619x; 3.1619x over previous
//
#include <hip/hip_runtime.h>
#include <math.h>
#include <stdint.h>

#define LAYERS 12
#define DMODEL 768
#define NHEAD 12
#define DHEAD 64
#define DFF 3072
#define BATCH 8
#define SEQ 512
#define NTOK (BATCH*SEQ)   /* 4096 */
#define KLEN 1024
#define SCALE 0.125f       /* 1/sqrt(64) */

typedef __bf16 bf16x8 __attribute__((ext_vector_type(8)));
typedef __bf16 bf16x4v __attribute__((ext_vector_type(4)));
typedef float f32x4 __attribute__((ext_vector_type(4)));

__device__ __forceinline__ void gld16(const void* g, void* l) {
  auto gp = reinterpret_cast<const __attribute__((address_space(1))) void*>(
      reinterpret_cast<uintptr_t>(g));
  auto lp = reinterpret_cast<__attribute__((address_space(3))) void*>(
      reinterpret_cast<uintptr_t>(l));
  __builtin_amdgcn_global_load_lds(gp, lp, 16, 0, 0);
}

// ---------------- embedding gather ----------------
__global__ void k_embed(const int* __restrict__ tox, const float* __restrict__ emb,
                        float* __restrict__ h, __bf16* __restrict__ hb) {
  int n = blockIdx.x;            // n = i*BATCH + b
  int i = n >> 3, b = n & 7;
  int tok = tox[b*SEQ + i];
  const float* src = emb + (size_t)tok * DMODEL;
  size_t off = (size_t)n * DMODEL;
  for (int d = threadIdx.x; d < DMODEL; d += blockDim.x) {
    float v = src[d];
    h[off+d] = v; hb[off+d] = (__bf16)v;
  }
}

// ---------------- positional encoding (bf16 out, GEMM input only) ----------------
__global__ void k_posenc(__bf16* __restrict__ r) {
  int idx = blockIdx.x * blockDim.x + threadIdx.x;
  if (idx >= KLEN * DMODEL) return;
  int k = idx / DMODEL, d = idx % DMODEL;
  float pos = (float)(SEQ - k);
  int j = (d < 384) ? d : d - 384;
  float invf = powf(10000.0f, -(2.0f * (float)j) / 768.0f);
  float a = pos * invf;
  r[idx] = (__bf16)((d < 384) ? sinf(a) : cosf(a));
}

// ---------------- weight transpose+convert: f32 [K][N] -> bf16 [N][K] ----------------
__global__ __launch_bounds__(256) void k_wt(const float* __restrict__ src, __bf16* __restrict__ dst,
                                            int srcN, int dstK, long sstride, long dstride, int drowoff) {
  __shared__ float t[32][33];
  int nt = blockIdx.x, kt = blockIdx.y, l = blockIdx.z;
  const float* s = src + (size_t)l * sstride;
  __bf16* d = dst + (size_t)l * dstride;
  int r = threadIdx.x >> 3, c4 = (threadIdx.x & 7) * 4;
  float4 v = *(const float4*)&s[(size_t)(kt*32 + r)*srcN + nt*32 + c4];
  t[r][c4+0]=v.x; t[r][c4+1]=v.y; t[r][c4+2]=v.z; t[r][c4+3]=v.w;
  __syncthreads();
  bf16x4v o = { (__bf16)t[c4+0][r], (__bf16)t[c4+1][r], (__bf16)t[c4+2][r], (__bf16)t[c4+3][r] };
  *(bf16x4v*)&d[(size_t)(drowoff + nt*32 + r)*dstK + kt*32 + c4] = o;
}

// ---------------- flat convert f32 -> bf16 (x4) ----------------
__global__ void k_cvt(const float* __restrict__ s, __bf16* __restrict__ d, int n4) {
  int i = blockIdx.x*256 + threadIdx.x;
  if (i >= n4) return;
  float4 v = ((const float4*)s)[i];
  bf16x4v o = { (__bf16)v.x, (__bf16)v.y, (__bf16)v.z, (__bf16)v.w };
  ((bf16x4v*)d)[i] = o;
}

// ---------------- MFMA GEMM: C[M,N] = A[M,K] @ B^T, B is [N][K] bf16 ----------------
// ACT: 0 none, 1 exact GELU.  OUTM: 0 f32, 1 bf16, 2 split f32 q/k/v (N=2304)
template<int ACT, int OUTM>
__global__ __launch_bounds__(256) void k_mgemm(
    const __bf16* __restrict__ A, const __bf16* __restrict__ B,
    const float* __restrict__ bias, void* __restrict__ Cv,
    float* __restrict__ oq, float* __restrict__ ok, float* __restrict__ ov,
    int M, int N, int K, long bz, long cz) {
  __shared__ __align__(16) __bf16 As[128*32];
  __shared__ __align__(16) __bf16 Bs[128*32];
  int tid = threadIdx.x;
  int wave = tid >> 6, lane = tid & 63;
  int lr = lane & 15, lc = lane >> 4;
  int wm = wave >> 1, wn = wave & 1;
  int m0 = blockIdx.y * 128, n0 = blockIdx.x * 128;
  const __bf16* Bp = B + (size_t)blockIdx.z * bz;

  f32x4 acc[4][4];
  #pragma unroll
  for (int i = 0; i < 4; ++i)
    #pragma unroll
    for (int j = 0; j < 4; ++j) acc[i][j] = f32x4{0.f,0.f,0.f,0.f};

  // staging source (swizzled chunk) per call
  int q0 = tid, q1 = 256 + tid;
  int r0 = q0 >> 2, s0 = (q0 & 3) ^ (r0 & 3);
  int r1 = q1 >> 2, s1 = (q1 & 3) ^ (r1 & 3);
  char* As0 = (char*)As + (size_t)(tid>>6)*1024;           // wave-uniform base, call 0
  char* Bs0 = (char*)Bs + (size_t)(tid>>6)*1024;

  for (int k0 = 0; k0 < K; k0 += 32) {
    __syncthreads();
    gld16(A  + (size_t)(m0 + r0)*K + k0 + s0*8, As0);
    gld16(A  + (size_t)(m0 + r1)*K + k0 + s1*8, As0 + 4096);
    gld16(Bp + (size_t)(n0 + r0)*K + k0 + s0*8, Bs0);
    gld16(Bp + (size_t)(n0 + r1)*K + k0 + s1*8, Bs0 + 4096);
    __syncthreads();
    bf16x8 af[4], bfr[4];
    #pragma unroll
    for (int mi = 0; mi < 4; ++mi) {
      int row = wm*64 + mi*16 + lr;
      af[mi] = *(const bf16x8*)((const char*)As + row*64 + ((lc ^ (row & 3))*16));
    }
    #pragma unroll
    for (int ni = 0; ni < 4; ++ni) {
      int row = wn*64 + ni*16 + lr;
      bfr[ni] = *(const bf16x8*)((const char*)Bs + row*64 + ((lc ^ (row & 3))*16));
    }
    #pragma unroll
    for (int mi = 0; mi < 4; ++mi)
      #pragma unroll
      for (int ni = 0; ni < 4; ++ni)
        acc[mi][ni] = __builtin_amdgcn_mfma_f32_16x16x32_bf16(af[mi], bfr[ni], acc[mi][ni], 0, 0, 0);
  }

  // epilogue: C/D layout col = lane&15, row = (lane>>4)*4 + j
  #pragma unroll
  for (int mi = 0; mi < 4; ++mi) {
    #pragma unroll
    for (int ni = 0; ni < 4; ++ni) {
      int gn = n0 + wn*64 + ni*16 + lr;
      float bv = (ACT == 1 || bias) ? (bias ? bias[gn] : 0.f) : 0.f;
      #pragma unroll
      for (int j = 0; j < 4; ++j) {
        int gm = m0 + wm*64 + mi*16 + lc*4 + j;
        float v = acc[mi][ni][j] + bv;
        if (ACT == 1) v = 0.5f*v*(1.0f + erff(v*0.70710678118654752f));
        if (OUTM == 0) {
          ((float*)Cv)[(size_t)blockIdx.z*cz + (size_t)gm*N + gn] = v;
        } else if (OUTM == 1) {
          ((__bf16*)Cv)[(size_t)blockIdx.z*cz + (size_t)gm*N + gn] = (__bf16)v;
        } else {
          float* dst; int col = gn;
          if (gn < 768) dst = oq;
          else if (gn < 1536) { dst = ok; col = gn - 768; }
          else { dst = ov; col = gn - 1536; }
          dst[(size_t)gm*768 + col] = v;
        }
      }
    }
  }
}

// ---------------- scalar fp32 GEMM for the tiny head (M=8) ----------------
template<int ACT>   // 0 none, 2 tanh
__global__ __launch_bounds__(256) void k_sgemm(
    const float* __restrict__ A, const float* __restrict__ W,
    const float* __restrict__ bias, float* __restrict__ C,
    int M, int N, int K) {
  const int BM = 128, BN = 64, BK = 16;
  __shared__ float As[BK][BM+4];
  __shared__ float Ws[BK][BN+4];
  int tid = threadIdx.x;
  int tx = tid & 15, ty = tid >> 4;
  int m0 = blockIdx.y * BM, n0 = blockIdx.x * BN;
  float acc[8][4];
  #pragma unroll
  for (int i = 0; i < 8; ++i)
    #pragma unroll
    for (int j = 0; j < 4; ++j) acc[i][j] = 0.f;
  for (int k0 = 0; k0 < K; k0 += BK) {
    {
      int c = tid & 15, rr0 = tid >> 4;
      #pragma unroll
      for (int p = 0; p < 8; ++p) {
        int rr = rr0 + p*16, gm = m0 + rr;
        As[c][rr] = (gm < M) ? A[(size_t)gm*K + (k0 + c)] : 0.f;
      }
    }
    {
      int c = tid & 63, rr0 = tid >> 6;
      #pragma unroll
      for (int p = 0; p < 4; ++p) {
        int rr = rr0 + p*4, gn = n0 + c;
        Ws[rr][c] = (gn < N) ? W[(size_t)(k0+rr)*N + gn] : 0.f;
      }
    }
    __syncthreads();
    #pragma unroll
    for (int k = 0; k < BK; ++k) {
      float a[8], b[4];
      #pragma unroll
      for (int i = 0; i < 8; ++i) a[i] = As[k][ty*8+i];
      #pragma unroll
      for (int j = 0; j < 4; ++j) b[j] = Ws[k][tx*4+j];
      #pragma unroll
      for (int i = 0; i < 8; ++i)
        #pragma unroll
        for (int j = 0; j < 4; ++j) acc[i][j] += a[i]*b[j];
    }
    __syncthreads();
  }
  #pragma unroll
  for (int i = 0; i < 8; ++i) {
    int gm = m0 + ty*8 + i;
    if (gm >= M) continue;
    #pragma unroll
    for (int j = 0; j < 4; ++j) {
      int gn = n0 + tx*4 + j;
      if (gn >= N) continue;
      float v = acc[i][j];
      if (bias) v += bias[gn];
      if (ACT == 2) v = tanhf(v);
      C[(size_t)gm*N + gn] = v;
    }
  }
}

// ---------------- relative attention (scalar flash), kr in bf16, out bf16 ----------------
#define ATI 128
#define ATJ 32
#define KRROWS (ATJ + ATI - 1)   /* 159 */

__global__ __launch_bounds__(128) void k_attn(
    const float* __restrict__ qh, const float* __restrict__ kh,
    const float* __restrict__ vh, const __bf16* __restrict__ kr,
    const float* __restrict__ rwb, const float* __restrict__ rrb,
    __bf16* __restrict__ vec) {
  int bid = blockIdx.x;
  int it = bid & 3;
  int bn = bid >> 2;
  int n = bn % NHEAD, b = bn / NHEAD;
  int i0 = it * ATI;
  int li = threadIdx.x;
  int i = i0 + li;

  __shared__ float kh_s[ATJ][64];
  __shared__ float vh_s[ATJ][64];
  __shared__ float kr_s[KRROWS*65];
  __shared__ float ck_s[ATJ];
  __shared__ float cr_s[KRROWS];
  __shared__ float rwb_s[64], rrb_s[64];

  if (li < 64) rwb_s[li] = rwb[n*64 + li];
  else         rrb_s[li-64] = rrb[n*64 + (li-64)];

  float q[64];
  {
    const float* qp = qh + (size_t)(i*BATCH + b)*DMODEL + n*64;
    #pragma unroll
    for (int d = 0; d < 64; ++d) q[d] = qp[d];
  }
  float acc[64];
  #pragma unroll
  for (int d = 0; d < 64; ++d) acc[d] = 0.f;
  float m = -1e30f, ssum = 0.f;

  __syncthreads();

  #pragma unroll 1
  for (int jt = 0; jt < SEQ/ATJ; ++jt) {
    int j0 = jt * ATJ;
    int kmin = j0 + SEQ - i0 - (ATI - 1);
    #pragma unroll
    for (int p = 0; p < 16; ++p) {
      int idx = li + p*128;
      int rr = idx >> 6, d = idx & 63;
      int j = j0 + rr;
      kh_s[rr][d] = kh[(size_t)(j*BATCH + b)*DMODEL + n*64 + d];
      vh_s[rr][d] = vh[(size_t)(j*BATCH + b)*DMODEL + n*64 + d];
    }
    for (int idx = li; idx < KRROWS*16; idx += 128) {
      int rr = idx >> 4, d4 = (idx & 15) << 2;
      bf16x4v v = *(const bf16x4v*)&kr[(size_t)(kmin + rr)*DMODEL + n*64 + d4];
      kr_s[rr*65 + d4 + 0] = (float)v[0];
      kr_s[rr*65 + d4 + 1] = (float)v[1];
      kr_s[rr*65 + d4 + 2] = (float)v[2];
      kr_s[rr*65 + d4 + 3] = (float)v[3];
    }
    __syncthreads();
    if (li < ATJ) {
      float s = 0.f;
      #pragma unroll
      for (int d = 0; d < 64; ++d) s += rwb_s[d]*kh_s[li][d];
      ck_s[li] = s;
    }
    for (int rr = li; rr < KRROWS; rr += 128) {
      float s = 0.f;
      #pragma unroll
      for (int d = 0; d < 64; ++d) s += rrb_s[d]*kr_s[rr*65 + d];
      cr_s[rr] = s;
    }
    __syncthreads();
    #pragma unroll 1
    for (int jj = 0; jj < ATJ; ++jj) {
      const float* khp = kh_s[jj];
      int krow = jj + (ATI-1) - li;
      const float* krp = &kr_s[krow*65];
      float s0=0.f, s1=0.f, s2=0.f, s3=0.f;
      #pragma unroll
      for (int d = 0; d < 64; d += 4) {
        s0 += q[d+0]*(khp[d+0]+krp[d+0]);
        s1 += q[d+1]*(khp[d+1]+krp[d+1]);
        s2 += q[d+2]*(khp[d+2]+krp[d+2]);
        s3 += q[d+3]*(khp[d+3]+krp[d+3]);
      }
      float s = (((s0+s1)+(s2+s3)) + ck_s[jj] + cr_s[krow]) * SCALE;
      if (s > m) {
        float f = __expf(m - s);
        ssum *= f;
        #pragma unroll
        for (int d = 0; d < 64; ++d) acc[d] *= f;
        m = s;
      }
      float p = __expf(s - m);
      ssum += p;
      const float* vp = vh_s[jj];
      #pragma unroll
      for (int d = 0; d < 64; ++d) acc[d] += p*vp[d];
    }
    __syncthreads();
  }
  float inv = 1.0f/ssum;
  __bf16* op = vec + (size_t)(i*BATCH + b)*DMODEL + n*64;
  #pragma unroll
  for (int d = 0; d < 64; ++d) op[d] = (__bf16)(acc[d]*inv);
}

// ---------------- LayerNorm(x + res) -> out fp32 + bf16 ----------------
__global__ __launch_bounds__(256) void k_ln_res(
    const float* __restrict__ x, const float* __restrict__ res,
    const float* __restrict__ g, const float* __restrict__ bta,
    float* __restrict__ out, __bf16* __restrict__ outb) {
  __shared__ float red[4];
  int row = blockIdx.x;
  size_t off = (size_t)row * DMODEL;
  int tid = threadIdx.x;
  float loc[3];
  float s = 0.f;
  #pragma unroll
  for (int p = 0; p < 3; ++p) {
    int d = tid + p*256;
    float v = x[off+d] + res[off+d];
    loc[p] = v; s += v;
  }
  #pragma unroll
  for (int o = 32; o; o >>= 1) s += __shfl_down(s, o, 64);
  if ((tid & 63) == 0) red[tid >> 6] = s;
  __syncthreads();
  float mean = (red[0]+red[1]+red[2]+red[3]) * (1.0f/DMODEL);
  __syncthreads();
  float vs = 0.f;
  #pragma unroll
  for (int p = 0; p < 3; ++p) { float d2 = loc[p] - mean; vs += d2*d2; }
  #pragma unroll
  for (int o = 32; o; o >>= 1) vs += __shfl_down(vs, o, 64);
  if ((tid & 63) == 0) red[tid >> 6] = vs;
  __syncthreads();
  float var = (red[0]+red[1]+red[2]+red[3]) * (1.0f/DMODEL);
  float rstd = 1.0f / sqrtf(var + 1e-12f);
  #pragma unroll
  for (int p = 0; p < 3; ++p) {
    int d = tid + p*256;
    float y = (loc[p]-mean)*rstd*g[d] + bta[d];
    out[off+d] = y;
    outb[off+d] = (__bf16)y;
  }
}

extern "C" void kernel_launch(void* const* d_in, const int* in_sizes, int n_in,
                              void* d_out, int out_size, void* d_ws, size_t ws_size,
                              hipStream_t stream) {
  (void)in_sizes; (void)n_in; (void)out_size; (void)ws_size;
  const int*   tox  = (const int*)d_in[0];
  const float* emb  = (const float*)d_in[3];
  const float* q_w  = (const float*)d_in[4];
  const float* k_w  = (const float*)d_in[5];
  const float* v_w  = (const float*)d_in[6];
  const float* o_w  = (const float*)d_in[7];
  const float* r_w  = (const float*)d_in[8];
  const float* rwb  = (const float*)d_in[9];
  const float* rrb  = (const float*)d_in[10];
  const float* ln1g = (const float*)d_in[11];
  const float* ln1b = (const float*)d_in[12];
  const float* fw1  = (const float*)d_in[13];
  const float* fb1  = (const float*)d_in[14];
  const float* fw2  = (const float*)d_in[15];
  const float* fb2  = (const float*)d_in[16];
  const float* ln2g = (const float*)d_in[17];
  const float* ln2b = (const float*)d_in[18];
  const float* sumw = (const float*)d_in[19];
  const float* sumb = (const float*)d_in[20];
  const float* pjw  = (const float*)d_in[21];
  const float* pjb  = (const float*)d_in[22];
  float* out = (float*)d_out;

  // ---- workspace bump allocator (256B aligned) ----
  char* wsp = (char*)d_ws;
  auto alloc = [&](size_t bytes) { char* rp = wsp; wsp += (bytes + 255) & ~(size_t)255; return rp; };
  float*  h      = (float*) alloc((size_t)NTOK*DMODEL*4);
  __bf16* h_bf   = (__bf16*)alloc((size_t)NTOK*DMODEL*2);
  float*  Qb     = (float*) alloc((size_t)NTOK*DMODEL*4);
  float*  Kb     = (float*) alloc((size_t)NTOK*DMODEL*4);
  float*  Vb     = (float*) alloc((size_t)NTOK*DMODEL*4);
  __bf16* vec_bf = (__bf16*)alloc((size_t)NTOK*DMODEL*2);
  float*  A5     = (float*) alloc((size_t)NTOK*DMODEL*4);
  __bf16* mid_bf = (__bf16*)alloc((size_t)NTOK*DFF*2);
  __bf16* r_bf   = (__bf16*)alloc((size_t)KLEN*DMODEL*2);
  __bf16* krb    = (__bf16*)alloc((size_t)LAYERS*KLEN*DMODEL*2);
  float*  summ   = (float*) alloc((size_t)BATCH*DMODEL*4);
  __bf16* qkvw   = (__bf16*)alloc((size_t)LAYERS*2304*768*2);
  __bf16* rwt    = (__bf16*)alloc((size_t)LAYERS*768*768*2);
  __bf16* owb    = (__bf16*)alloc((size_t)LAYERS*768*768*2);
  __bf16* ff1t   = (__bf16*)alloc((size_t)LAYERS*768*3072*2);
  __bf16* ff2t   = (__bf16*)alloc((size_t)LAYERS*3072*768*2);

  dim3 b256(256);
  // ---- weight convert/transpose (per-launch; ~550 MB traffic) ----
  k_wt<<<dim3(24,24,LAYERS), b256, 0, stream>>>(q_w, qkvw, 768, 768, 589824, 2304*768, 0);
  k_wt<<<dim3(24,24,LAYERS), b256, 0, stream>>>(k_w, qkvw, 768, 768, 589824, 2304*768, 768);
  k_wt<<<dim3(24,24,LAYERS), b256, 0, stream>>>(v_w, qkvw, 768, 768, 589824, 2304*768, 1536);
  k_wt<<<dim3(24,24,LAYERS), b256, 0, stream>>>(r_w, rwt, 768, 768, 589824, 589824, 0);
  k_wt<<<dim3(96,24,LAYERS), b256, 0, stream>>>(fw1, ff1t, 3072, 768, (long)768*3072, (long)3072*768, 0);
  k_wt<<<dim3(24,96,LAYERS), b256, 0, stream>>>(fw2, ff2t, 768, 3072, (long)3072*768, (long)768*3072, 0);
  k_cvt<<<(LAYERS*589824/4 + 255)/256, b256, 0, stream>>>(o_w, owb, LAYERS*589824/4);

  k_embed<<<NTOK, b256, 0, stream>>>(tox, emb, h, h_bf);
  k_posenc<<<(KLEN*DMODEL + 255)/256, b256, 0, stream>>>(r_bf);

  // kr for all layers in one launch: [L][1024][768] bf16
  k_mgemm<0,1><<<dim3(6,8,LAYERS), b256, 0, stream>>>(r_bf, rwt, nullptr, krb,
      nullptr, nullptr, nullptr, KLEN, 768, 768, (long)589824, (long)KLEN*DMODEL);

  for (int l = 0; l < LAYERS; ++l) {
    k_mgemm<0,2><<<dim3(18,32), b256, 0, stream>>>(h_bf, qkvw + (size_t)l*2304*768, nullptr, nullptr,
        Qb, Kb, Vb, NTOK, 2304, 768, 0, 0);
    k_attn<<<BATCH*NHEAD*4, dim3(128), 0, stream>>>(Qb, Kb, Vb, krb + (size_t)l*KLEN*DMODEL,
        rwb + l*DMODEL, rrb + l*DMODEL, vec_bf);
    k_mgemm<0,0><<<dim3(6,32), b256, 0, stream>>>(vec_bf, owb + (size_t)l*589824, nullptr, A5,
        nullptr, nullptr, nullptr, NTOK, 768, 768, 0, 0);
    k_ln_res<<<NTOK, b256, 0, stream>>>(A5, h, ln1g + l*DMODEL, ln1b + l*DMODEL, h, h_bf);
    k_mgemm<1,1><<<dim3(24,32), b256, 0, stream>>>(h_bf, ff1t + (size_t)l*768*3072, fb1 + (size_t)l*DFF, mid_bf,
        nullptr, nullptr, nullptr, NTOK, DFF, 768, 0, 0);
    k_mgemm<0,0><<<dim3(6,32), b256, 0, stream>>>(mid_bf, ff2t + (size_t)l*3072*768, fb2 + l*DMODEL, A5,
        nullptr, nullptr, nullptr, NTOK, 768, DFF, 0, 0);
    k_ln_res<<<NTOK, b256, 0, stream>>>(A5, h, ln2g + l*DMODEL, ln2b + l*DMODEL, h, h_bf);
  }

  const float* lastp = h + (size_t)(NTOK - BATCH)*DMODEL;
  k_sgemm<2><<<dim3(DMODEL/64, 1), b256, 0, stream>>>(lastp, sumw, sumb, summ, BATCH, DMODEL, DMODEL);
  k_sgemm<0><<<dim3(1, 1), b256, 0, stream>>>(summ, pjw, pjb, out, BATCH, 2, DMODEL);
}

// Round 3
// 3655.104 us; speedup vs baseline: 7.9614x; 2.5179x over previous
//
#include <hip/hip_runtime.h>
#include <math.h>
#include <stdint.h>

#define LAYERS 12
#define DMODEL 768
#define NHEAD 12
#define DHEAD 64
#define DFF 3072
#define BATCH 8
#define SEQ 512
#define NTOK (BATCH*SEQ)   /* 4096 */
#define KLEN 1024
#define SCALE 0.125f       /* 1/sqrt(64) */

typedef __bf16 bf16x8 __attribute__((ext_vector_type(8)));
typedef __bf16 bf16x4v __attribute__((ext_vector_type(4)));
typedef float f32x4 __attribute__((ext_vector_type(4)));

__device__ __forceinline__ void gld16(const void* g, void* l) {
  auto gp = reinterpret_cast<const __attribute__((address_space(1))) void*>(
      reinterpret_cast<uintptr_t>(g));
  auto lp = reinterpret_cast<__attribute__((address_space(3))) void*>(
      reinterpret_cast<uintptr_t>(l));
  __builtin_amdgcn_global_load_lds(gp, lp, 16, 0, 0);
}

// ---------------- embedding gather ----------------
__global__ void k_embed(const int* __restrict__ tox, const float* __restrict__ emb,
                        float* __restrict__ h, __bf16* __restrict__ hb) {
  int n = blockIdx.x;            // n = i*BATCH + b
  int i = n >> 3, b = n & 7;
  int tok = tox[b*SEQ + i];
  const float* src = emb + (size_t)tok * DMODEL;
  size_t off = (size_t)n * DMODEL;
  for (int d = threadIdx.x; d < DMODEL; d += blockDim.x) {
    float v = src[d];
    h[off+d] = v; hb[off+d] = (__bf16)v;
  }
}

// ---------------- positional encoding (bf16, GEMM input only) ----------------
__global__ void k_posenc(__bf16* __restrict__ r) {
  int idx = blockIdx.x * blockDim.x + threadIdx.x;
  if (idx >= KLEN * DMODEL) return;
  int k = idx / DMODEL, d = idx % DMODEL;
  float pos = (float)(SEQ - k);
  int j = (d < 384) ? d : d - 384;
  float invf = powf(10000.0f, -(2.0f * (float)j) / 768.0f);
  float a = pos * invf;
  r[idx] = (__bf16)((d < 384) ? sinf(a) : cosf(a));
}

// ---------------- weight transpose+convert: f32 [K][N] -> bf16 [N][K] ----------------
__global__ __launch_bounds__(256) void k_wt(const float* __restrict__ src, __bf16* __restrict__ dst,
                                            int srcN, int dstK, long sstride, long dstride, int drowoff) {
  __shared__ float t[32][33];
  int nt = blockIdx.x, kt = blockIdx.y, l = blockIdx.z;
  const float* s = src + (size_t)l * sstride;
  __bf16* d = dst + (size_t)l * dstride;
  int r = threadIdx.x >> 3, c4 = (threadIdx.x & 7) * 4;
  float4 v = *(const float4*)&s[(size_t)(kt*32 + r)*srcN + nt*32 + c4];
  t[r][c4+0]=v.x; t[r][c4+1]=v.y; t[r][c4+2]=v.z; t[r][c4+3]=v.w;
  __syncthreads();
  bf16x4v o = { (__bf16)t[c4+0][r], (__bf16)t[c4+1][r], (__bf16)t[c4+2][r], (__bf16)t[c4+3][r] };
  *(bf16x4v*)&d[(size_t)(drowoff + nt*32 + r)*dstK + kt*32 + c4] = o;
}

// ---------------- flat convert f32 -> bf16 (x4) ----------------
__global__ void k_cvt(const float* __restrict__ s, __bf16* __restrict__ d, int n4) {
  int i = blockIdx.x*256 + threadIdx.x;
  if (i >= n4) return;
  float4 v = ((const float4*)s)[i];
  bf16x4v o = { (__bf16)v.x, (__bf16)v.y, (__bf16)v.z, (__bf16)v.w };
  ((bf16x4v*)d)[i] = o;
}

// ---------------- V transpose: vb[4096][768] head-cols -> vtg[bn][64][512] ----------------
__global__ __launch_bounds__(256) void k_vt(const __bf16* __restrict__ vb, __bf16* __restrict__ vtg) {
  __shared__ __bf16 t[32][36];
  int it = blockIdx.x, dt = blockIdx.y, bn = blockIdx.z;
  int b = bn / 12, n = bn % 12;
  int r = threadIdx.x >> 3, c4 = (threadIdx.x & 7) * 4;
  // read 32 rows(i) x 32 cols(d)
  bf16x4v v = *(const bf16x4v*)&vb[((size_t)(it*32 + r)*8 + b)*768 + n*64 + dt*32 + c4];
  t[r][c4+0]=v[0]; t[r][c4+1]=v[1]; t[r][c4+2]=v[2]; t[r][c4+3]=v[3];
  __syncthreads();
  bf16x4v o = { t[c4+0][r], t[c4+1][r], t[c4+2][r], t[c4+3][r] };
  *(bf16x4v*)&vtg[((size_t)bn*64 + dt*32 + r)*512 + it*32 + c4] = o;
}

// ---------------- MFMA GEMM: C[M,N] = A[M,K] @ B^T, B is [N][K] bf16 ----------------
// ACT: 0 none, 1 exact GELU.  OUTM: 0 f32, 1 bf16, 2 QKV split (N=2304, bf16 x4 + biases)
template<int ACT, int OUTM>
__global__ __launch_bounds__(256) void k_mgemm(
    const __bf16* __restrict__ A, const __bf16* __restrict__ B,
    const float* __restrict__ bias, void* __restrict__ Cv,
    __bf16* __restrict__ q1, __bf16* __restrict__ q2,
    __bf16* __restrict__ kk, __bf16* __restrict__ vv,
    const float* __restrict__ rwbp, const float* __restrict__ rrbp,
    int M, int N, int K, long bz, long cz) {
  __shared__ __align__(16) __bf16 As[128*32];
  __shared__ __align__(16) __bf16 Bs[128*32];
  int tid = threadIdx.x;
  int wave = tid >> 6, lane = tid & 63;
  int lr = lane & 15, lc = lane >> 4;
  int wm = wave >> 1, wn = wave & 1;
  int m0 = blockIdx.y * 128, n0 = blockIdx.x * 128;
  const __bf16* Bp = B + (size_t)blockIdx.z * bz;

  f32x4 acc[4][4];
  #pragma unroll
  for (int i = 0; i < 4; ++i)
    #pragma unroll
    for (int j = 0; j < 4; ++j) acc[i][j] = f32x4{0.f,0.f,0.f,0.f};

  int q0 = tid, q1i = 256 + tid;
  int r0 = q0 >> 2, s0 = (q0 & 3) ^ (r0 & 3);
  int r1 = q1i >> 2, s1 = (q1i & 3) ^ (r1 & 3);
  char* As0 = (char*)As + (size_t)wave*1024;
  char* Bs0 = (char*)Bs + (size_t)wave*1024;

  for (int k0 = 0; k0 < K; k0 += 32) {
    __syncthreads();
    gld16(A  + (size_t)(m0 + r0)*K + k0 + s0*8, As0);
    gld16(A  + (size_t)(m0 + r1)*K + k0 + s1*8, As0 + 4096);
    gld16(Bp + (size_t)(n0 + r0)*K + k0 + s0*8, Bs0);
    gld16(Bp + (size_t)(n0 + r1)*K + k0 + s1*8, Bs0 + 4096);
    __syncthreads();
    bf16x8 af[4], bfr[4];
    #pragma unroll
    for (int mi = 0; mi < 4; ++mi) {
      int row = wm*64 + mi*16 + lr;
      af[mi] = *(const bf16x8*)((const char*)As + row*64 + ((lc ^ (row & 3))*16));
    }
    #pragma unroll
    for (int ni = 0; ni < 4; ++ni) {
      int row = wn*64 + ni*16 + lr;
      bfr[ni] = *(const bf16x8*)((const char*)Bs + row*64 + ((lc ^ (row & 3))*16));
    }
    #pragma unroll
    for (int mi = 0; mi < 4; ++mi)
      #pragma unroll
      for (int ni = 0; ni < 4; ++ni)
        acc[mi][ni] = __builtin_amdgcn_mfma_f32_16x16x32_bf16(af[mi], bfr[ni], acc[mi][ni], 0, 0, 0);
  }

  #pragma unroll
  for (int mi = 0; mi < 4; ++mi) {
    #pragma unroll
    for (int ni = 0; ni < 4; ++ni) {
      int gn = n0 + wn*64 + ni*16 + lr;
      float bv = bias ? bias[gn] : 0.f;
      #pragma unroll
      for (int j = 0; j < 4; ++j) {
        int gm = m0 + wm*64 + mi*16 + lc*4 + j;
        float v = acc[mi][ni][j] + bv;
        if (ACT == 1) v = 0.5f*v*(1.0f + erff(v*0.70710678118654752f));
        if (OUTM == 0) {
          ((float*)Cv)[(size_t)blockIdx.z*cz + (size_t)gm*N + gn] = v;
        } else if (OUTM == 1) {
          ((__bf16*)Cv)[(size_t)blockIdx.z*cz + (size_t)gm*N + gn] = (__bf16)v;
        } else {
          if (gn < 768) {
            size_t o = (size_t)gm*768 + gn;
            q1[o] = (__bf16)(v + rwbp[gn]);
            q2[o] = (__bf16)(v + rrbp[gn]);
          } else if (gn < 1536) {
            kk[(size_t)gm*768 + gn - 768] = (__bf16)v;
          } else {
            vv[(size_t)gm*768 + gn - 1536] = (__bf16)v;
          }
        }
      }
    }
  }
}

// ---------------- BD GEMM: S[bn][i][j] = SCALE * (qrr_i . kr_{j+512-i}) ----------------
// grid (5 ktiles, 4 itiles, 96 bn); output written via diagonal remap j = k-512+i
__global__ __launch_bounds__(256) void k_bd(
    const __bf16* __restrict__ qrr, const __bf16* __restrict__ krb,
    __bf16* __restrict__ S) {
  __shared__ __align__(16) __bf16 As[128*64];
  __shared__ __align__(16) __bf16 Bs[128*64];
  int tid = threadIdx.x;
  int wave = tid >> 6, lane = tid & 63;
  int lr = lane & 15, lc = lane >> 4;
  int wm = wave >> 1, wn = wave & 1;
  int bn = blockIdx.z;
  int b = bn / 12, n = bn % 12;
  int i0 = blockIdx.y * 128;
  int kbase = 384 - i0;
  int n0k = kbase + blockIdx.x * 128;

  // stage A (qrr rows i0..i0+128, 64 dims) and B (kr rows n0k.., 64 dims)
  #pragma unroll
  for (int c = 0; c < 4; ++c) {
    int id = c*256 + tid;
    int row = id >> 3, cc = (id & 7) ^ (row & 7);
    gld16(qrr + ((size_t)(i0 + row)*8 + b)*768 + n*64 + cc*8,
          (char*)As + (size_t)c*4096 + (size_t)wave*1024);
  }
  #pragma unroll
  for (int c = 0; c < 4; ++c) {
    int id = c*256 + tid;
    int row = id >> 3, cc = (id & 7) ^ (row & 7);
    gld16(krb + (size_t)(n0k + row)*768 + n*64 + cc*8,
          (char*)Bs + (size_t)c*4096 + (size_t)wave*1024);
  }
  __syncthreads();

  f32x4 acc[4][4];
  #pragma unroll
  for (int i = 0; i < 4; ++i)
    #pragma unroll
    for (int j = 0; j < 4; ++j) acc[i][j] = f32x4{0.f,0.f,0.f,0.f};

  #pragma unroll
  for (int ks = 0; ks < 2; ++ks) {
    bf16x8 af[4], bfr[4];
    #pragma unroll
    for (int mi = 0; mi < 4; ++mi) {
      int row = wm*64 + mi*16 + lr;
      af[mi] = *(const bf16x8*)((const char*)As + row*128 + (((ks*4 + lc) ^ (row & 7))*16));
    }
    #pragma unroll
    for (int ni = 0; ni < 4; ++ni) {
      int row = wn*64 + ni*16 + lr;
      bfr[ni] = *(const bf16x8*)((const char*)Bs + row*128 + (((ks*4 + lc) ^ (row & 7))*16));
    }
    #pragma unroll
    for (int mi = 0; mi < 4; ++mi)
      #pragma unroll
      for (int ni = 0; ni < 4; ++ni)
        acc[mi][ni] = __builtin_amdgcn_mfma_f32_16x16x32_bf16(af[mi], bfr[ni], acc[mi][ni], 0, 0, 0);
  }

  size_t sbase = (size_t)bn * 512 * 512;
  #pragma unroll
  for (int mi = 0; mi < 4; ++mi) {
    #pragma unroll
    for (int ni = 0; ni < 4; ++ni) {
      int gkl = wn*64 + ni*16 + lr;
      int gk = n0k + gkl;
      #pragma unroll
      for (int j = 0; j < 4; ++j) {
        int gi = i0 + wm*64 + mi*16 + lc*4 + j;
        int gj = gk - 512 + gi;
        if ((unsigned)gj < 512u)
          S[sbase + (size_t)gi*512 + gj] = (__bf16)(acc[mi][ni][j] * SCALE);
      }
    }
  }
}

// ---------------- flash attention PV: AC mfma + bd + online softmax + PV mfma ----------------
// grid (8 itiles of 64, 96 bn), block 256 (4 waves, 16 queries each)
__global__ __launch_bounds__(256) void k_pv(
    const __bf16* __restrict__ qrw, const __bf16* __restrict__ kb,
    const __bf16* __restrict__ vtg, const __bf16* __restrict__ S,
    __bf16* __restrict__ vec) {
  __shared__ __align__(16) char lds[32768];
  // layout: [0,8K) K-tile (union: Q-tile at start), [8K,16K) Vt, [16K,24K) bd, [24K,32K) P (2KB/wave)
  int tid = threadIdx.x;
  int w = tid >> 6, lane = tid & 63;
  int lr = lane & 15, lg = lane >> 4;     // lr = this lane's query (softmax) / col; lg = group
  int bn = blockIdx.y;
  int b = bn / 12, n = bn % 12;
  int i0 = blockIdx.x * 64;

  // ---- stage Q tile [64 q][64 d] into lds[0..8K) ----
  #pragma unroll
  for (int c = 0; c < 2; ++c) {
    int id = c*256 + tid;
    int row = id >> 3, cc = (id & 7) ^ (row & 7);
    gld16(qrw + ((size_t)(i0 + row)*8 + b)*768 + n*64 + cc*8,
          lds + (size_t)c*4096 + (size_t)w*1024);
  }
  __syncthreads();
  // Q B-frags (per wave fixed): row = w*16+lr, k-chunk = lg + ks*4
  bf16x8 qf[2];
  #pragma unroll
  for (int ks = 0; ks < 2; ++ks) {
    int row = w*16 + lr;
    qf[ks] = *(const bf16x8*)(lds + row*128 + (((lg + ks*4) ^ (row & 7))*16));
  }

  f32x4 O[4];
  #pragma unroll
  for (int d = 0; d < 4; ++d) O[d] = f32x4{0.f,0.f,0.f,0.f};
  float m_run = -1e30f, den = 0.f;
  char* Plds = lds + 24576 + w*2048;

  for (int jt = 0; jt < 8; ++jt) {
    int j0 = jt * 64;
    __syncthreads();   // prior tile fully consumed (incl. Q-frag reads on first iter)
    // stage K [64 j][64 d], Vt [64 d][64 j], bd [64 q][64 j]
    #pragma unroll
    for (int c = 0; c < 2; ++c) {
      int id = c*256 + tid;
      int row = id >> 3, cc = (id & 7) ^ (row & 7);
      gld16(kb + ((size_t)(j0 + row)*8 + b)*768 + n*64 + cc*8,
            lds + (size_t)c*4096 + (size_t)w*1024);
      gld16(vtg + ((size_t)bn*64 + row)*512 + j0 + cc*8,
            lds + 8192 + (size_t)c*4096 + (size_t)w*1024);
      gld16(S + ((size_t)bn*512 + i0 + row)*512 + j0 + cc*8,
            lds + 16384 + (size_t)c*4096 + (size_t)w*1024);
    }
    __syncthreads();

    // ---- AC: mfma(K, Q): D[row=key][col=q] ----
    f32x4 acf[4];
    #pragma unroll
    for (int ksub = 0; ksub < 4; ++ksub) acf[ksub] = f32x4{0.f,0.f,0.f,0.f};
    #pragma unroll
    for (int ks = 0; ks < 2; ++ks) {
      #pragma unroll
      for (int ksub = 0; ksub < 4; ++ksub) {
        int row = ksub*16 + lr;
        bf16x8 kf = *(const bf16x8*)(lds + row*128 + (((lg + ks*4) ^ (row & 7))*16));
        acf[ksub] = __builtin_amdgcn_mfma_f32_16x16x32_bf16(kf, qf[ks], acf[ksub], 0, 0, 0);
      }
    }
    // lane holds scores: q = lr (wave-local), keys = ksub*16 + lg*4 + r
    // ---- add bd, softmax ----
    float sc[4][4];
    float mt = -1e30f;
    int qrow = w*16 + lr;
    #pragma unroll
    for (int ksub = 0; ksub < 4; ++ksub) {
      int k = ksub*16 + lg*4;
      bf16x4v bdv = *(const bf16x4v*)(lds + 16384 + qrow*128 +
                     (((k >> 3) ^ (qrow & 7))*16) + (k & 7)*2);
      #pragma unroll
      for (int r = 0; r < 4; ++r) {
        float s = acf[ksub][r]*SCALE + (float)bdv[r];
        sc[ksub][r] = s;
        mt = fmaxf(mt, s);
      }
    }
    mt = fmaxf(mt, __shfl_xor(mt, 16));
    mt = fmaxf(mt, __shfl_xor(mt, 32));
    float m_new = fmaxf(m_run, mt);
    float f = __expf(m_run - m_new);
    m_run = m_new;
    float psum = 0.f;
    #pragma unroll
    for (int ksub = 0; ksub < 4; ++ksub) {
      bf16x4v pv;
      #pragma unroll
      for (int r = 0; r < 4; ++r) {
        float p = __expf(sc[ksub][r] - m_new);
        psum += p;
        pv[r] = (__bf16)p;
      }
      int k = ksub*16 + lg*4;
      *(bf16x4v*)(Plds + lr*128 + (((k >> 3) ^ (lr & 7))*16) + (k & 7)*2) = pv;
    }
    den = den*f + psum;
    // rescale O by f (per output row q' = lg*4 + j)
    float fv[4];
    #pragma unroll
    for (int j = 0; j < 4; ++j) fv[j] = __shfl(f, lg*4 + j);
    #pragma unroll
    for (int d = 0; d < 4; ++d)
      #pragma unroll
      for (int j = 0; j < 4; ++j) O[d][j] *= fv[j];
    // ---- PV: mfma(P, Vt): D[row=q][col=d] ----
    #pragma unroll
    for (int ks = 0; ks < 2; ++ks) {
      bf16x8 paf = *(const bf16x8*)(Plds + lr*128 + (((lg + ks*4) ^ (lr & 7))*16));
      #pragma unroll
      for (int d = 0; d < 4; ++d) {
        int row = d*16 + lr;
        bf16x8 vf = *(const bf16x8*)(lds + 8192 + row*128 + (((lg + ks*4) ^ (row & 7))*16));
        O[d] = __builtin_amdgcn_mfma_f32_16x16x32_bf16(paf, vf, O[d], 0, 0, 0);
      }
    }
  }

  // totals across the 4-lane groups
  den += __shfl_xor(den, 16);
  den += __shfl_xor(den, 32);
  float inv = 1.0f / den;
  float iv[4];
  #pragma unroll
  for (int j = 0; j < 4; ++j) iv[j] = __shfl(inv, lg*4 + j);
  #pragma unroll
  for (int d = 0; d < 4; ++d) {
    #pragma unroll
    for (int j = 0; j < 4; ++j) {
      int qg = i0 + w*16 + lg*4 + j;
      int dd = d*16 + lr;
      vec[((size_t)qg*8 + b)*768 + n*64 + dd] = (__bf16)(O[d][j] * iv[j]);
    }
  }
}

// ---------------- scalar fp32 GEMM for the tiny head (M=8) ----------------
template<int ACT>   // 0 none, 2 tanh
__global__ __launch_bounds__(256) void k_sgemm(
    const float* __restrict__ A, const float* __restrict__ W,
    const float* __restrict__ bias, float* __restrict__ C,
    int M, int N, int K) {
  const int BM = 128, BN = 64, BK = 16;
  __shared__ float As[BK][BM+4];
  __shared__ float Ws[BK][BN+4];
  int tid = threadIdx.x;
  int tx = tid & 15, ty = tid >> 4;
  int m0 = blockIdx.y * BM, n0 = blockIdx.x * BN;
  float acc[8][4];
  #pragma unroll
  for (int i = 0; i < 8; ++i)
    #pragma unroll
    for (int j = 0; j < 4; ++j) acc[i][j] = 0.f;
  for (int k0 = 0; k0 < K; k0 += BK) {
    {
      int c = tid & 15, rr0 = tid >> 4;
      #pragma unroll
      for (int p = 0; p < 8; ++p) {
        int rr = rr0 + p*16, gm = m0 + rr;
        As[c][rr] = (gm < M) ? A[(size_t)gm*K + (k0 + c)] : 0.f;
      }
    }
    {
      int c = tid & 63, rr0 = tid >> 6;
      #pragma unroll
      for (int p = 0; p < 4; ++p) {
        int rr = rr0 + p*4, gn = n0 + c;
        Ws[rr][c] = (gn < N) ? W[(size_t)(k0+rr)*N + gn] : 0.f;
      }
    }
    __syncthreads();
    #pragma unroll
    for (int k = 0; k < BK; ++k) {
      float a[8], bv[4];
      #pragma unroll
      for (int i = 0; i < 8; ++i) a[i] = As[k][ty*8+i];
      #pragma unroll
      for (int j = 0; j < 4; ++j) bv[j] = Ws[k][tx*4+j];
      #pragma unroll
      for (int i = 0; i < 8; ++i)
        #pragma unroll
        for (int j = 0; j < 4; ++j) acc[i][j] += a[i]*bv[j];
    }
    __syncthreads();
  }
  #pragma unroll
  for (int i = 0; i < 8; ++i) {
    int gm = m0 + ty*8 + i;
    if (gm >= M) continue;
    #pragma unroll
    for (int j = 0; j < 4; ++j) {
      int gn = n0 + tx*4 + j;
      if (gn >= N) continue;
      float v = acc[i][j];
      if (bias) v += bias[gn];
      if (ACT == 2) v = tanhf(v);
      C[(size_t)gm*N + gn] = v;
    }
  }
}

// ---------------- LayerNorm(x + res) -> out fp32 + bf16 ----------------
__global__ __launch_bounds__(256) void k_ln_res(
    const float* __restrict__ x, const float* __restrict__ res,
    const float* __restrict__ g, const float* __restrict__ bta,
    float* __restrict__ out, __bf16* __restrict__ outb) {
  __shared__ float red[4];
  int row = blockIdx.x;
  size_t off = (size_t)row * DMODEL;
  int tid = threadIdx.x;
  float loc[3];
  float s = 0.f;
  #pragma unroll
  for (int p = 0; p < 3; ++p) {
    int d = tid + p*256;
    float v = x[off+d] + res[off+d];
    loc[p] = v; s += v;
  }
  #pragma unroll
  for (int o = 32; o; o >>= 1) s += __shfl_down(s, o, 64);
  if ((tid & 63) == 0) red[tid >> 6] = s;
  __syncthreads();
  float mean = (red[0]+red[1]+red[2]+red[3]) * (1.0f/DMODEL);
  __syncthreads();
  float vs = 0.f;
  #pragma unroll
  for (int p = 0; p < 3; ++p) { float d2 = loc[p] - mean; vs += d2*d2; }
  #pragma unroll
  for (int o = 32; o; o >>= 1) vs += __shfl_down(vs, o, 64);
  if ((tid & 63) == 0) red[tid >> 6] = vs;
  __syncthreads();
  float var = (red[0]+red[1]+red[2]+red[3]) * (1.0f/DMODEL);
  float rstd = 1.0f / sqrtf(var + 1e-12f);
  #pragma unroll
  for (int p = 0; p < 3; ++p) {
    int d = tid + p*256;
    float y = (loc[p]-mean)*rstd*g[d] + bta[d];
    out[off+d] = y;
    outb[off+d] = (__bf16)y;
  }
}

extern "C" void kernel_launch(void* const* d_in, const int* in_sizes, int n_in,
                              void* d_out, int out_size, void* d_ws, size_t ws_size,
                              hipStream_t stream) {
  (void)in_sizes; (void)n_in; (void)out_size; (void)ws_size;
  const int*   tox  = (const int*)d_in[0];
  const float* emb  = (const float*)d_in[3];
  const float* q_w  = (const float*)d_in[4];
  const float* k_w  = (const float*)d_in[5];
  const float* v_w  = (const float*)d_in[6];
  const float* o_w  = (const float*)d_in[7];
  const float* r_w  = (const float*)d_in[8];
  const float* rwb  = (const float*)d_in[9];
  const float* rrb  = (const float*)d_in[10];
  const float* ln1g = (const float*)d_in[11];
  const float* ln1b = (const float*)d_in[12];
  const float* fw1  = (const float*)d_in[13];
  const float* fb1  = (const float*)d_in[14];
  const float* fw2  = (const float*)d_in[15];
  const float* fb2  = (const float*)d_in[16];
  const float* ln2g = (const float*)d_in[17];
  const float* ln2b = (const float*)d_in[18];
  const float* sumw = (const float*)d_in[19];
  const float* sumb = (const float*)d_in[20];
  const float* pjw  = (const float*)d_in[21];
  const float* pjb  = (const float*)d_in[22];
  float* out = (float*)d_out;

  // ---- workspace bump allocator (256B aligned), ~288 MB total ----
  char* wsp = (char*)d_ws;
  auto alloc = [&](size_t bytes) { char* rp = wsp; wsp += (bytes + 255) & ~(size_t)255; return rp; };
  __bf16* qkvw   = (__bf16*)alloc((size_t)LAYERS*2304*768*2);
  __bf16* rwt    = (__bf16*)alloc((size_t)LAYERS*768*768*2);
  __bf16* owb    = (__bf16*)alloc((size_t)LAYERS*768*768*2);
  __bf16* ff1t   = (__bf16*)alloc((size_t)LAYERS*768*3072*2);
  __bf16* ff2t   = (__bf16*)alloc((size_t)LAYERS*3072*768*2);
  float*  h      = (float*) alloc((size_t)NTOK*DMODEL*4);
  __bf16* h_bf   = (__bf16*)alloc((size_t)NTOK*DMODEL*2);
  __bf16* r_bf   = (__bf16*)alloc((size_t)KLEN*DMODEL*2);
  __bf16* krb    = (__bf16*)alloc((size_t)KLEN*DMODEL*2);
  __bf16* qrw    = (__bf16*)alloc((size_t)NTOK*DMODEL*2);
  __bf16* qrr    = (__bf16*)alloc((size_t)NTOK*DMODEL*2);
  __bf16* kbuf   = (__bf16*)alloc((size_t)NTOK*DMODEL*2);
  __bf16* vtg    = (__bf16*)alloc((size_t)96*64*512*2);
  __bf16* vec_bf = (__bf16*)alloc((size_t)NTOK*DMODEL*2);
  float*  summ   = (float*) alloc((size_t)BATCH*DMODEL*4);
  // aliased region: S (96*512*512 bf16 = 50.33MB) over [mid_bf 25.17 | A5 12.58 | vb 6.29]
  char*   Sreg   = alloc((size_t)96*512*512*2);
  __bf16* S      = (__bf16*)Sreg;
  __bf16* mid_bf = (__bf16*)Sreg;
  float*  A5     = (float*)(Sreg + (size_t)NTOK*DFF*2);
  __bf16* vb     = (__bf16*)(Sreg + (size_t)NTOK*DFF*2 + (size_t)NTOK*DMODEL*4);

  dim3 b256(256);
  // ---- weight convert/transpose ----
  k_wt<<<dim3(24,24,LAYERS), b256, 0, stream>>>(q_w, qkvw, 768, 768, 589824, 2304*768, 0);
  k_wt<<<dim3(24,24,LAYERS), b256, 0, stream>>>(k_w, qkvw, 768, 768, 589824, 2304*768, 768);
  k_wt<<<dim3(24,24,LAYERS), b256, 0, stream>>>(v_w, qkvw, 768, 768, 589824, 2304*768, 1536);
  k_wt<<<dim3(24,24,LAYERS), b256, 0, stream>>>(r_w, rwt, 768, 768, 589824, 589824, 0);
  k_wt<<<dim3(96,24,LAYERS), b256, 0, stream>>>(fw1, ff1t, 3072, 768, (long)768*3072, (long)3072*768, 0);
  k_wt<<<dim3(24,96,LAYERS), b256, 0, stream>>>(fw2, ff2t, 768, 3072, (long)3072*768, (long)768*3072, 0);
  k_cvt<<<(LAYERS*589824/4 + 255)/256, b256, 0, stream>>>(o_w, owb, LAYERS*589824/4);

  k_embed<<<NTOK, b256, 0, stream>>>(tox, emb, h, h_bf);
  k_posenc<<<(KLEN*DMODEL + 255)/256, b256, 0, stream>>>(r_bf);

  for (int l = 0; l < LAYERS; ++l) {
    // QKV fused (writes qrw/qrr with biases, kbuf, vb)
    k_mgemm<0,2><<<dim3(18,32), b256, 0, stream>>>(h_bf, qkvw + (size_t)l*2304*768, nullptr, nullptr,
        qrw, qrr, kbuf, vb, rwb + l*DMODEL, rrb + l*DMODEL, NTOK, 2304, 768, 0, 0);
    // V transpose to [bn][64][512]
    k_vt<<<dim3(16,2,96), b256, 0, stream>>>(vb, vtg);
    // kr = r @ r_w^T for this layer
    k_mgemm<0,1><<<dim3(6,8), b256, 0, stream>>>(r_bf, rwt + (size_t)l*589824, nullptr, krb,
        nullptr, nullptr, nullptr, nullptr, nullptr, nullptr, KLEN, 768, 768, 0, 0);
    // BD: S = SCALE * qrr @ kr^T (diagonal remap)
    k_bd<<<dim3(5,4,96), b256, 0, stream>>>(qrr, krb, S);
    // flash attention
    k_pv<<<dim3(8,96), b256, 0, stream>>>(qrw, kbuf, vtg, S, vec_bf);
    // O projection
    k_mgemm<0,0><<<dim3(6,32), b256, 0, stream>>>(vec_bf, owb + (size_t)l*589824, nullptr, A5,
        nullptr, nullptr, nullptr, nullptr, nullptr, nullptr, NTOK, 768, 768, 0, 0);
    k_ln_res<<<NTOK, b256, 0, stream>>>(A5, h, ln1g + l*DMODEL, ln1b + l*DMODEL, h, h_bf);
    // FF
    k_mgemm<1,1><<<dim3(24,32), b256, 0, stream>>>(h_bf, ff1t + (size_t)l*768*3072, fb1 + (size_t)l*DFF, mid_bf,
        nullptr, nullptr, nullptr, nullptr, nullptr, nullptr, NTOK, DFF, 768, 0, 0);
    k_mgemm<0,0><<<dim3(6,32), b256, 0, stream>>>(mid_bf, ff2t + (size_t)l*3072*768, fb2 + l*DMODEL, A5,
        nullptr, nullptr, nullptr, nullptr, nullptr, nullptr, NTOK, 768, DFF, 0, 0);
    k_ln_res<<<NTOK, b256, 0, stream>>>(A5, h, ln2g + l*DMODEL, ln2b + l*DMODEL, h, h_bf);
  }

  const float* lastp = h + (size_t)(NTOK - BATCH)*DMODEL;
  k_sgemm<2><<<dim3(DMODEL/64, 1), b256, 0, stream>>>(lastp, sumw, sumb, summ, BATCH, DMODEL, DMODEL);
  k_sgemm<0><<<dim3(1, 1), b256, 0, stream>>>(summ, pjw, pjb, out, BATCH, 2, DMODEL);
}

// Round 4
// 2639.429 us; speedup vs baseline: 11.0251x; 1.3848x over previous
//
#include <hip/hip_runtime.h>
#include <math.h>
#include <stdint.h>

#define LAYERS 12
#define DMODEL 768
#define NHEAD 12
#define DHEAD 64
#define DFF 3072
#define BATCH 8
#define SEQ 512
#define NTOK (BATCH*SEQ)   /* 4096 */
#define KLEN 1024
#define SCALE 0.125f       /* 1/sqrt(64) */

typedef __bf16 bf16x8 __attribute__((ext_vector_type(8)));
typedef __bf16 bf16x4v __attribute__((ext_vector_type(4)));
typedef float f32x4 __attribute__((ext_vector_type(4)));

__device__ __forceinline__ void gld16(const void* g, void* l) {
  auto gp = reinterpret_cast<const __attribute__((address_space(1))) void*>(
      reinterpret_cast<uintptr_t>(g));
  auto lp = reinterpret_cast<__attribute__((address_space(3))) void*>(
      reinterpret_cast<uintptr_t>(l));
  __builtin_amdgcn_global_load_lds(gp, lp, 16, 0, 0);
}

// ---------------- embedding gather ----------------
__global__ void k_embed(const int* __restrict__ tox, const float* __restrict__ emb,
                        float* __restrict__ h, __bf16* __restrict__ hb) {
  int n = blockIdx.x;            // n = i*BATCH + b
  int i = n >> 3, b = n & 7;
  int tok = tox[b*SEQ + i];
  const float* src = emb + (size_t)tok * DMODEL;
  size_t off = (size_t)n * DMODEL;
  for (int d = threadIdx.x; d < DMODEL; d += blockDim.x) {
    float v = src[d];
    h[off+d] = v; hb[off+d] = (__bf16)v;
  }
}

// ---------------- positional encoding (bf16, GEMM input only) ----------------
__global__ void k_posenc(__bf16* __restrict__ r) {
  int idx = blockIdx.x * blockDim.x + threadIdx.x;
  if (idx >= KLEN * DMODEL) return;
  int k = idx / DMODEL, d = idx % DMODEL;
  float pos = (float)(SEQ - k);
  int j = (d < 384) ? d : d - 384;
  float invf = powf(10000.0f, -(2.0f * (float)j) / 768.0f);
  float a = pos * invf;
  r[idx] = (__bf16)((d < 384) ? sinf(a) : cosf(a));
}

// ---------------- weight transpose+convert: f32 [K][N] -> bf16 [N][K] ----------------
__global__ __launch_bounds__(256) void k_wt(const float* __restrict__ src, __bf16* __restrict__ dst,
                                            int srcN, int dstK, long sstride, long dstride, int drowoff) {
  __shared__ float t[32][33];
  int nt = blockIdx.x, kt = blockIdx.y, l = blockIdx.z;
  const float* s = src + (size_t)l * sstride;
  __bf16* d = dst + (size_t)l * dstride;
  int r = threadIdx.x >> 3, c4 = (threadIdx.x & 7) * 4;
  float4 v = *(const float4*)&s[(size_t)(kt*32 + r)*srcN + nt*32 + c4];
  t[r][c4+0]=v.x; t[r][c4+1]=v.y; t[r][c4+2]=v.z; t[r][c4+3]=v.w;
  __syncthreads();
  bf16x4v o = { (__bf16)t[c4+0][r], (__bf16)t[c4+1][r], (__bf16)t[c4+2][r], (__bf16)t[c4+3][r] };
  *(bf16x4v*)&d[(size_t)(drowoff + nt*32 + r)*dstK + kt*32 + c4] = o;
}

// ---------------- flat convert f32 -> bf16 (x4) ----------------
__global__ void k_cvt(const float* __restrict__ s, __bf16* __restrict__ d, int n4) {
  int i = blockIdx.x*256 + threadIdx.x;
  if (i >= n4) return;
  float4 v = ((const float4*)s)[i];
  bf16x4v o = { (__bf16)v.x, (__bf16)v.y, (__bf16)v.z, (__bf16)v.w };
  ((bf16x4v*)d)[i] = o;
}

// ---------------- V transpose: vb[4096][768] head-cols -> vtg[bn][64][512] ----------------
__global__ __launch_bounds__(256) void k_vt(const __bf16* __restrict__ vb, __bf16* __restrict__ vtg) {
  __shared__ __bf16 t[32][36];
  int it = blockIdx.x, dt = blockIdx.y, bn = blockIdx.z;
  int b = bn / 12, n = bn % 12;
  int r = threadIdx.x >> 3, c4 = (threadIdx.x & 7) * 4;
  bf16x4v v = *(const bf16x4v*)&vb[((size_t)(it*32 + r)*8 + b)*768 + n*64 + dt*32 + c4];
  t[r][c4+0]=v[0]; t[r][c4+1]=v[1]; t[r][c4+2]=v[2]; t[r][c4+3]=v[3];
  __syncthreads();
  bf16x4v o = { t[c4+0][r], t[c4+1][r], t[c4+2][r], t[c4+3][r] };
  *(bf16x4v*)&vtg[((size_t)bn*64 + dt*32 + r)*512 + it*32 + c4] = o;
}

// ---------------- MFMA GEMM: C[M,N] = A[M,K] @ B^T, B is [N][K] bf16 ----------------
// ACT: 0 none, 1 exact GELU.  OUTM: 0 f32 (+z*cz), 1 bf16 (+z*cz), 2 QKV split
// SPLITK: 1 normal (z selects B/C slab), >1: z selects K-slice, partials to z*cz
template<int ACT, int OUTM, int SPLITK>
__global__ __launch_bounds__(256) void k_mgemm(
    const __bf16* __restrict__ A, const __bf16* __restrict__ B,
    const float* __restrict__ bias, void* __restrict__ Cv,
    __bf16* __restrict__ q1, __bf16* __restrict__ q2,
    __bf16* __restrict__ kk, __bf16* __restrict__ vv,
    const float* __restrict__ rwbp, const float* __restrict__ rrbp,
    int M, int N, int K, long bz, long cz) {
  __shared__ __align__(16) __bf16 As[128*32];
  __shared__ __align__(16) __bf16 Bs[128*32];
  int tid = threadIdx.x;
  int wave = tid >> 6, lane = tid & 63;
  int lr = lane & 15, lc = lane >> 4;
  int wm = wave >> 1, wn = wave & 1;
  int m0 = blockIdx.y * 128, n0 = blockIdx.x * 128;
  const __bf16* Bp = B + (SPLITK > 1 ? 0 : (size_t)blockIdx.z * bz);
  int kbeg = (SPLITK > 1) ? blockIdx.z * (K/SPLITK) : 0;
  int kend = (SPLITK > 1) ? kbeg + K/SPLITK : K;

  f32x4 acc[4][4];
  #pragma unroll
  for (int i = 0; i < 4; ++i)
    #pragma unroll
    for (int j = 0; j < 4; ++j) acc[i][j] = f32x4{0.f,0.f,0.f,0.f};

  int q0 = tid, q1i = 256 + tid;
  int r0 = q0 >> 2, s0 = (q0 & 3) ^ (r0 & 3);
  int r1 = q1i >> 2, s1 = (q1i & 3) ^ (r1 & 3);
  char* As0 = (char*)As + (size_t)wave*1024;
  char* Bs0 = (char*)Bs + (size_t)wave*1024;

  for (int k0 = kbeg; k0 < kend; k0 += 32) {
    __syncthreads();
    gld16(A  + (size_t)(m0 + r0)*K + k0 + s0*8, As0);
    gld16(A  + (size_t)(m0 + r1)*K + k0 + s1*8, As0 + 4096);
    gld16(Bp + (size_t)(n0 + r0)*K + k0 + s0*8, Bs0);
    gld16(Bp + (size_t)(n0 + r1)*K + k0 + s1*8, Bs0 + 4096);
    __syncthreads();
    bf16x8 af[4], bfr[4];
    #pragma unroll
    for (int mi = 0; mi < 4; ++mi) {
      int row = wm*64 + mi*16 + lr;
      af[mi] = *(const bf16x8*)((const char*)As + row*64 + ((lc ^ (row & 3))*16));
    }
    #pragma unroll
    for (int ni = 0; ni < 4; ++ni) {
      int row = wn*64 + ni*16 + lr;
      bfr[ni] = *(const bf16x8*)((const char*)Bs + row*64 + ((lc ^ (row & 3))*16));
    }
    #pragma unroll
    for (int mi = 0; mi < 4; ++mi)
      #pragma unroll
      for (int ni = 0; ni < 4; ++ni)
        acc[mi][ni] = __builtin_amdgcn_mfma_f32_16x16x32_bf16(af[mi], bfr[ni], acc[mi][ni], 0, 0, 0);
  }

  #pragma unroll
  for (int mi = 0; mi < 4; ++mi) {
    #pragma unroll
    for (int ni = 0; ni < 4; ++ni) {
      int gn = n0 + wn*64 + ni*16 + lr;
      float bv = (bias && (SPLITK == 1 || blockIdx.z == 0)) ? bias[gn] : 0.f;
      #pragma unroll
      for (int j = 0; j < 4; ++j) {
        int gm = m0 + wm*64 + mi*16 + lc*4 + j;
        float v = acc[mi][ni][j] + bv;
        if (ACT == 1) v = 0.5f*v*(1.0f + erff(v*0.70710678118654752f));
        if (OUTM == 0) {
          ((float*)Cv)[(size_t)blockIdx.z*cz + (size_t)gm*N + gn] = v;
        } else if (OUTM == 1) {
          ((__bf16*)Cv)[(size_t)blockIdx.z*cz + (size_t)gm*N + gn] = (__bf16)v;
        } else {
          if (gn < 768) {
            size_t o = (size_t)gm*768 + gn;
            q1[o] = (__bf16)(v + rwbp[gn]);
            q2[o] = (__bf16)(v + rrbp[gn]);
          } else if (gn < 1536) {
            kk[(size_t)gm*768 + gn - 768] = (__bf16)v;
          } else {
            vv[(size_t)gm*768 + gn - 1536] = (__bf16)v;
          }
        }
      }
    }
  }
}

// ---------------- fused flash attention: AC mfma + BD mfma (rel-shift) + softmax + PV ----------------
// grid (8 itiles of 64, 96 bn), block 256 (4 waves, 16 queries each)
__global__ __launch_bounds__(256) void k_pv(
    const __bf16* __restrict__ qrw, const __bf16* __restrict__ qrr,
    const __bf16* __restrict__ kb, const __bf16* __restrict__ vtg,
    const __bf16* __restrict__ krb, __bf16* __restrict__ vec) {
  // LDS: KT 8K @0 | VT 8K @8192 | KR 16K @16384 | BD 64x68 bf16 @32768 (8704) | P @41472 (2K/wave)
  __shared__ __align__(16) char lds[49664];
  int tid = threadIdx.x;
  int w = tid >> 6, lane = tid & 63;
  int lr = lane & 15, lg = lane >> 4;
  int bn = blockIdx.y;
  int b = bn / 12, n = bn % 12;
  int i0 = blockIdx.x * 64;
  char* KT = lds;
  char* VT = lds + 8192;
  char* KR = lds + 16384;
  char* BD = lds + 32768;
  char* Plds = lds + 41472 + w*2048;

  // ---- stage qrw tile into KT, qrr tile into VT; read both frags ----
  #pragma unroll
  for (int c = 0; c < 2; ++c) {
    int id = c*256 + tid;
    int row = id >> 3, cc = (id & 7) ^ (row & 7);
    gld16(qrw + ((size_t)(i0 + row)*8 + b)*768 + n*64 + cc*8, KT + c*4096 + w*1024);
    gld16(qrr + ((size_t)(i0 + row)*8 + b)*768 + n*64 + cc*8, VT + c*4096 + w*1024);
  }
  __syncthreads();
  bf16x8 qwf[2], qrf[2];
  #pragma unroll
  for (int ks = 0; ks < 2; ++ks) {
    int row = w*16 + lr;
    qwf[ks] = *(const bf16x8*)(KT + row*128 + (((lg + ks*4) ^ (row & 7))*16));
    qrf[ks] = *(const bf16x8*)(VT + row*128 + (((lg + ks*4) ^ (row & 7))*16));
  }

  f32x4 O[4];
  #pragma unroll
  for (int d = 0; d < 4; ++d) O[d] = f32x4{0.f,0.f,0.f,0.f};
  float m_run = -1e30f, den = 0.f;

  for (int jt = 0; jt < 8; ++jt) {
    int j0 = jt * 64;
    int kw0 = j0 - i0 + 449;           // kr window base (rows kw0..kw0+127)
    __syncthreads();                    // prev tile consumed (and Q frags read on iter 0)
    // stage K [64][64], Vt [64][64], KR window [128][64]
    #pragma unroll
    for (int c = 0; c < 2; ++c) {
      int id = c*256 + tid;
      int row = id >> 3, cc = (id & 7) ^ (row & 7);
      gld16(kb + ((size_t)(j0 + row)*8 + b)*768 + n*64 + cc*8, KT + c*4096 + w*1024);
      gld16(vtg + ((size_t)bn*64 + row)*512 + j0 + cc*8, VT + c*4096 + w*1024);
    }
    #pragma unroll
    for (int c = 0; c < 4; ++c) {
      int id = c*256 + tid;
      int row = id >> 3, cc = (id & 7) ^ (row & 7);
      gld16(krb + (size_t)(kw0 + row)*768 + n*64 + cc*8, KR + c*4096 + w*1024);
    }
    __syncthreads();

    __builtin_amdgcn_s_setprio(1);
    // ---- AC: mfma(K, Qw): lane holds q = lr, keys = ksub*16 + lg*4 + r ----
    f32x4 acf[4];
    #pragma unroll
    for (int ksub = 0; ksub < 4; ++ksub) acf[ksub] = f32x4{0.f,0.f,0.f,0.f};
    #pragma unroll
    for (int ks = 0; ks < 2; ++ks) {
      #pragma unroll
      for (int ksub = 0; ksub < 4; ++ksub) {
        int row = ksub*16 + lr;
        bf16x8 kf = *(const bf16x8*)(KT + row*128 + (((lg + ks*4) ^ (row & 7))*16));
        acf[ksub] = __builtin_amdgcn_mfma_f32_16x16x32_bf16(kf, qwf[ks], acf[ksub], 0, 0, 0);
      }
    }
    // ---- BD: mfma(Qr, KRwin): lane holds i16 = lg*4+jreg, kloc = kt*16+lr ----
    // scatter to BD[i_local][jloc], jloc = kloc + i_local - 63
    #pragma unroll
    for (int kt = 0; kt < 8; ++kt) {
      f32x4 bda = f32x4{0.f,0.f,0.f,0.f};
      #pragma unroll
      for (int ks = 0; ks < 2; ++ks) {
        int rowk = kt*16 + lr;
        bf16x8 krf = *(const bf16x8*)(KR + rowk*128 + (((lg + ks*4) ^ (rowk & 7))*16));
        bda = __builtin_amdgcn_mfma_f32_16x16x32_bf16(qrf[ks], krf, bda, 0, 0, 0);
      }
      #pragma unroll
      for (int jreg = 0; jreg < 4; ++jreg) {
        int il = w*16 + lg*4 + jreg;              // i_local in [0,64)
        int jloc = kt*16 + lr + il - 63;
        if ((unsigned)jloc < 64u)
          *(__bf16*)(BD + (il*68 + jloc)*2) = (__bf16)bda[jreg];
      }
    }
    __builtin_amdgcn_s_setprio(0);

    // ---- softmax (lane owns query q = lr of wave w) ----
    float sc[4][4];
    float mt = -1e30f;
    int qrow = w*16 + lr;
    #pragma unroll
    for (int ksub = 0; ksub < 4; ++ksub) {
      bf16x4v bdv = *(const bf16x4v*)(BD + (qrow*68 + ksub*16 + lg*4)*2);
      #pragma unroll
      for (int r = 0; r < 4; ++r) {
        float s = (acf[ksub][r] + (float)bdv[r]) * SCALE;
        sc[ksub][r] = s;
        mt = fmaxf(mt, s);
      }
    }
    mt = fmaxf(mt, __shfl_xor(mt, 16));
    mt = fmaxf(mt, __shfl_xor(mt, 32));
    float m_new = fmaxf(m_run, mt);
    float f = __expf(m_run - m_new);
    m_run = m_new;
    float psum = 0.f;
    #pragma unroll
    for (int ksub = 0; ksub < 4; ++ksub) {
      bf16x4v pv;
      #pragma unroll
      for (int r = 0; r < 4; ++r) {
        float p = __expf(sc[ksub][r] - m_new);
        psum += p;
        pv[r] = (__bf16)p;
      }
      int k = ksub*16 + lg*4;
      *(bf16x4v*)(Plds + lr*128 + (((k >> 3) ^ (lr & 7))*16) + (k & 7)*2) = pv;
    }
    den = den*f + psum;
    float fv[4];
    #pragma unroll
    for (int j = 0; j < 4; ++j) fv[j] = __shfl(f, lg*4 + j);
    #pragma unroll
    for (int d = 0; d < 4; ++d)
      #pragma unroll
      for (int j = 0; j < 4; ++j) O[d][j] *= fv[j];
    // ---- PV: mfma(P, Vt): D[row=q][col=d] ----
    __builtin_amdgcn_s_setprio(1);
    #pragma unroll
    for (int ks = 0; ks < 2; ++ks) {
      bf16x8 paf = *(const bf16x8*)(Plds + lr*128 + (((lg + ks*4) ^ (lr & 7))*16));
      #pragma unroll
      for (int d = 0; d < 4; ++d) {
        int row = d*16 + lr;
        bf16x8 vf = *(const bf16x8*)(VT + row*128 + (((lg + ks*4) ^ (row & 7))*16));
        O[d] = __builtin_amdgcn_mfma_f32_16x16x32_bf16(paf, vf, O[d], 0, 0, 0);
      }
    }
    __builtin_amdgcn_s_setprio(0);
  }

  den += __shfl_xor(den, 16);
  den += __shfl_xor(den, 32);
  float inv = 1.0f / den;
  float iv[4];
  #pragma unroll
  for (int j = 0; j < 4; ++j) iv[j] = __shfl(inv, lg*4 + j);
  #pragma unroll
  for (int d = 0; d < 4; ++d) {
    #pragma unroll
    for (int j = 0; j < 4; ++j) {
      int qg = i0 + w*16 + lg*4 + j;
      int dd = d*16 + lr;
      vec[((size_t)qg*8 + b)*768 + n*64 + dd] = (__bf16)(O[d][j] * iv[j]);
    }
  }
}

// ---------------- head: summ = tanh(last[8][768] @ sumw + sumb) ----------------
__global__ __launch_bounds__(256) void k_head1(
    const float* __restrict__ last, const float* __restrict__ sumw,
    const float* __restrict__ sumb, float* __restrict__ summ) {
  __shared__ float red[256];
  int tid = threadIdx.x;
  int nn = blockIdx.x*16 + (tid & 15);
  int r = (tid >> 4) & 7;
  int half = tid >> 7;
  const float* lp = last + (size_t)r*768 + half*384;
  const float* wp = sumw + (size_t)half*384*768 + nn;
  float s = 0.f;
  #pragma unroll 4
  for (int k = 0; k < 384; ++k) s += lp[k] * wp[(size_t)k*768];
  red[tid] = s;
  __syncthreads();
  if (tid < 128) {
    float t = red[tid] + red[tid + 128];
    summ[(size_t)r*768 + nn] = tanhf(t + sumb[nn]);
  }
}

// ---------------- head: out = summ[8][768] @ pjw[768][2] + pjb ----------------
__global__ __launch_bounds__(128) void k_head2(
    const float* __restrict__ summ, const float* __restrict__ pjw,
    const float* __restrict__ pjb, float* __restrict__ out) {
  __shared__ float red[128];
  int tid = threadIdx.x;
  int o = tid & 15;           // output index: r = o>>1, c = o&1
  int r = o >> 1, c = o & 1;
  int seg = tid >> 4;         // 8 segments of 96
  float s = 0.f;
  #pragma unroll 4
  for (int k = seg*96; k < seg*96 + 96; ++k) s += summ[(size_t)r*768 + k] * pjw[(size_t)k*2 + c];
  red[tid] = s;
  __syncthreads();
  if (tid < 16) {
    float t = 0.f;
    #pragma unroll
    for (int sg = 0; sg < 8; ++sg) t += red[sg*16 + tid];
    out[tid] = t + pjb[tid & 1];
  }
}

// ---------------- LayerNorm(x [+ x2] + res) -> out fp32 + bf16 (192 thr, float4) ----------------
template<int HASX2>
__global__ __launch_bounds__(192) void k_ln_res(
    const float* __restrict__ x, const float* __restrict__ x2,
    const float* __restrict__ res, const float* __restrict__ g,
    const float* __restrict__ bta, float* __restrict__ out, __bf16* __restrict__ outb) {
  __shared__ float red[6];
  int row = blockIdx.x, tid = threadIdx.x;
  size_t off = (size_t)row*768 + tid*4;
  float4 v = *(const float4*)(x + off);
  if (HASX2) {
    float4 u = *(const float4*)(x2 + off);
    v.x += u.x; v.y += u.y; v.z += u.z; v.w += u.w;
  }
  {
    float4 u = *(const float4*)(res + off);
    v.x += u.x; v.y += u.y; v.z += u.z; v.w += u.w;
  }
  float s = v.x + v.y + v.z + v.w;
  #pragma unroll
  for (int o = 32; o; o >>= 1) s += __shfl_down(s, o, 64);
  if ((tid & 63) == 0) red[tid >> 6] = s;
  __syncthreads();
  float mean = (red[0] + red[1] + red[2]) * (1.0f/768.0f);
  float a0 = v.x - mean, a1 = v.y - mean, a2 = v.z - mean, a3 = v.w - mean;
  float vs = a0*a0 + a1*a1 + a2*a2 + a3*a3;
  #pragma unroll
  for (int o = 32; o; o >>= 1) vs += __shfl_down(vs, o, 64);
  if ((tid & 63) == 0) red[3 + (tid >> 6)] = vs;
  __syncthreads();
  float var = (red[3] + red[4] + red[5]) * (1.0f/768.0f);
  float rstd = 1.0f / sqrtf(var + 1e-12f);
  float4 gv = *(const float4*)(g + tid*4);
  float4 bv = *(const float4*)(bta + tid*4);
  float4 y;
  y.x = a0*rstd*gv.x + bv.x;
  y.y = a1*rstd*gv.y + bv.y;
  y.z = a2*rstd*gv.z + bv.z;
  y.w = a3*rstd*gv.w + bv.w;
  *(float4*)(out + off) = y;
  bf16x4v yb = { (__bf16)y.x, (__bf16)y.y, (__bf16)y.z, (__bf16)y.w };
  *(bf16x4v*)(outb + off) = yb;
}

extern "C" void kernel_launch(void* const* d_in, const int* in_sizes, int n_in,
                              void* d_out, int out_size, void* d_ws, size_t ws_size,
                              hipStream_t stream) {
  (void)in_sizes; (void)n_in; (void)out_size; (void)ws_size;
  const int*   tox  = (const int*)d_in[0];
  const float* emb  = (const float*)d_in[3];
  const float* q_w  = (const float*)d_in[4];
  const float* k_w  = (const float*)d_in[5];
  const float* v_w  = (const float*)d_in[6];
  const float* o_w  = (const float*)d_in[7];
  const float* r_w  = (const float*)d_in[8];
  const float* rwb  = (const float*)d_in[9];
  const float* rrb  = (const float*)d_in[10];
  const float* ln1g = (const float*)d_in[11];
  const float* ln1b = (const float*)d_in[12];
  const float* fw1  = (const float*)d_in[13];
  const float* fb1  = (const float*)d_in[14];
  const float* fw2  = (const float*)d_in[15];
  const float* fb2  = (const float*)d_in[16];
  const float* ln2g = (const float*)d_in[17];
  const float* ln2b = (const float*)d_in[18];
  const float* sumw = (const float*)d_in[19];
  const float* sumb = (const float*)d_in[20];
  const float* pjw  = (const float*)d_in[21];
  const float* pjb  = (const float*)d_in[22];
  float* out = (float*)d_out;

  // ---- workspace bump allocator (256B aligned), ~287 MB total ----
  char* wsp = (char*)d_ws;
  auto alloc = [&](size_t bytes) { char* rp = wsp; wsp += (bytes + 255) & ~(size_t)255; return rp; };
  __bf16* qkvw   = (__bf16*)alloc((size_t)LAYERS*2304*768*2);
  __bf16* rwt    = (__bf16*)alloc((size_t)LAYERS*768*768*2);
  __bf16* owb    = (__bf16*)alloc((size_t)LAYERS*768*768*2);
  __bf16* ff1t   = (__bf16*)alloc((size_t)LAYERS*768*3072*2);
  __bf16* ff2t   = (__bf16*)alloc((size_t)LAYERS*3072*768*2);
  float*  h      = (float*) alloc((size_t)NTOK*DMODEL*4);
  __bf16* h_bf   = (__bf16*)alloc((size_t)NTOK*DMODEL*2);
  __bf16* r_bf   = (__bf16*)alloc((size_t)KLEN*DMODEL*2);
  __bf16* krb    = (__bf16*)alloc(((size_t)LAYERS*KLEN + 8)*DMODEL*2);  // +pad rows (window overreach)
  __bf16* vtg    = (__bf16*)alloc((size_t)96*64*512*2);
  __bf16* vec_bf = (__bf16*)alloc((size_t)NTOK*DMODEL*2);
  float*  A5     = (float*) alloc((size_t)2*NTOK*DMODEL*4);   // two split-K halves, contiguous
  float*  summ   = (float*) alloc((size_t)BATCH*DMODEL*4);
  // union region (25.17 MB): qrw|qrr|kbuf|vb, aliased by mid_bf (dead by FF1 time)
  char*   U      = alloc((size_t)NTOK*DMODEL*2 * 4);
  __bf16* qrw    = (__bf16*)U;
  __bf16* qrr    = (__bf16*)(U + (size_t)NTOK*DMODEL*2);
  __bf16* kbuf   = (__bf16*)(U + (size_t)NTOK*DMODEL*2*2);
  __bf16* vb     = (__bf16*)(U + (size_t)NTOK*DMODEL*2*3);
  __bf16* mid_bf = (__bf16*)U;

  dim3 b256(256);
  // ---- weight convert/transpose ----
  k_wt<<<dim3(24,24,LAYERS), b256, 0, stream>>>(q_w, qkvw, 768, 768, 589824, 2304*768, 0);
  k_wt<<<dim3(24,24,LAYERS), b256, 0, stream>>>(k_w, qkvw, 768, 768, 589824, 2304*768, 768);
  k_wt<<<dim3(24,24,LAYERS), b256, 0, stream>>>(v_w, qkvw, 768, 768, 589824, 2304*768, 1536);
  k_wt<<<dim3(24,24,LAYERS), b256, 0, stream>>>(r_w, rwt, 768, 768, 589824, 589824, 0);
  k_wt<<<dim3(96,24,LAYERS), b256, 0, stream>>>(fw1, ff1t, 3072, 768, (long)768*3072, (long)3072*768, 0);
  k_wt<<<dim3(24,96,LAYERS), b256, 0, stream>>>(fw2, ff2t, 768, 3072, (long)3072*768, (long)768*3072, 0);
  k_cvt<<<(LAYERS*589824/4 + 255)/256, b256, 0, stream>>>(o_w, owb, LAYERS*589824/4);

  k_embed<<<NTOK, b256, 0, stream>>>(tox, emb, h, h_bf);
  k_posenc<<<(KLEN*DMODEL + 255)/256, b256, 0, stream>>>(r_bf);

  // kr for ALL layers in one dispatch: [L][1024][768] bf16
  k_mgemm<0,1,1><<<dim3(6,8,LAYERS), b256, 0, stream>>>(r_bf, rwt, nullptr, krb,
      nullptr, nullptr, nullptr, nullptr, nullptr, nullptr,
      KLEN, 768, 768, (long)589824, (long)KLEN*DMODEL);

  for (int l = 0; l < LAYERS; ++l) {
    // QKV fused (writes qrw/qrr with biases, kbuf, vb)
    k_mgemm<0,2,1><<<dim3(18,32), b256, 0, stream>>>(h_bf, qkvw + (size_t)l*2304*768, nullptr, nullptr,
        qrw, qrr, kbuf, vb, rwb + l*DMODEL, rrb + l*DMODEL, NTOK, 2304, 768, 0, 0);
    // V transpose to [bn][64][512]
    k_vt<<<dim3(16,2,96), b256, 0, stream>>>(vb, vtg);
    // fused attention (AC + BD + softmax + PV)
    k_pv<<<dim3(8,96), b256, 0, stream>>>(qrw, qrr, kbuf, vtg,
        krb + (size_t)l*KLEN*DMODEL, vec_bf);
    // O projection
    k_mgemm<0,0,1><<<dim3(6,32), b256, 0, stream>>>(vec_bf, owb + (size_t)l*589824, nullptr, A5,
        nullptr, nullptr, nullptr, nullptr, nullptr, nullptr, NTOK, 768, 768, 0, 0);
    k_ln_res<0><<<NTOK, dim3(192), 0, stream>>>(A5, nullptr, h, ln1g + l*DMODEL, ln1b + l*DMODEL, h, h_bf);
    // FF
    k_mgemm<1,1,1><<<dim3(24,32), b256, 0, stream>>>(h_bf, ff1t + (size_t)l*768*3072, fb1 + (size_t)l*DFF, mid_bf,
        nullptr, nullptr, nullptr, nullptr, nullptr, nullptr, NTOK, DFF, 768, 0, 0);
    k_mgemm<0,0,2><<<dim3(6,32,2), b256, 0, stream>>>(mid_bf, ff2t + (size_t)l*3072*768, fb2 + l*DMODEL, A5,
        nullptr, nullptr, nullptr, nullptr, nullptr, nullptr, NTOK, 768, DFF, 0, (long)NTOK*DMODEL);
    k_ln_res<1><<<NTOK, dim3(192), 0, stream>>>(A5, A5 + (size_t)NTOK*DMODEL, h,
        ln2g + l*DMODEL, ln2b + l*DMODEL, h, h_bf);
  }

  const float* lastp = h + (size_t)(NTOK - BATCH)*DMODEL;
  k_head1<<<dim3(48), b256, 0, stream>>>(lastp, sumw, sumb, summ);
  k_head2<<<dim3(1), dim3(128), 0, stream>>>(summ, pjw, pjb, out);
}

// Round 5
// 2340.848 us; speedup vs baseline: 12.4313x; 1.1276x over previous
//
#include <hip/hip_runtime.h>
#include <math.h>
#include <stdint.h>

#define LAYERS 12
#define DMODEL 768
#define NHEAD 12
#define DHEAD 64
#define DFF 3072
#define BATCH 8
#define SEQ 512
#define NTOK (BATCH*SEQ)   /* 4096 */
#define KLEN 1024
#define SCALE 0.125f       /* 1/sqrt(64) */

typedef __bf16 bf16x8 __attribute__((ext_vector_type(8)));
typedef __bf16 bf16x4v __attribute__((ext_vector_type(4)));
typedef float f32x4 __attribute__((ext_vector_type(4)));

__device__ __forceinline__ void gld16(const void* g, void* l) {
  auto gp = reinterpret_cast<const __attribute__((address_space(1))) void*>(
      reinterpret_cast<uintptr_t>(g));
  auto lp = reinterpret_cast<__attribute__((address_space(3))) void*>(
      reinterpret_cast<uintptr_t>(l));
  __builtin_amdgcn_global_load_lds(gp, lp, 16, 0, 0);
}

// ---------------- embedding gather ----------------
__global__ void k_embed(const int* __restrict__ tox, const float* __restrict__ emb,
                        float* __restrict__ h, __bf16* __restrict__ hb) {
  int n = blockIdx.x;            // n = i*BATCH + b
  int i = n >> 3, b = n & 7;
  int tok = tox[b*SEQ + i];
  const float* src = emb + (size_t)tok * DMODEL;
  size_t off = (size_t)n * DMODEL;
  for (int d = threadIdx.x; d < DMODEL; d += blockDim.x) {
    float v = src[d];
    h[off+d] = v; hb[off+d] = (__bf16)v;
  }
}

// ---------------- positional encoding (bf16, GEMM input only) ----------------
__global__ void k_posenc(__bf16* __restrict__ r) {
  int idx = blockIdx.x * blockDim.x + threadIdx.x;
  if (idx >= KLEN * DMODEL) return;
  int k = idx / DMODEL, d = idx % DMODEL;
  float pos = (float)(SEQ - k);
  int j = (d < 384) ? d : d - 384;
  float invf = powf(10000.0f, -(2.0f * (float)j) / 768.0f);
  float a = pos * invf;
  r[idx] = (__bf16)((d < 384) ? sinf(a) : cosf(a));
}

// ---------------- weight transpose+convert: f32 [K][N] -> bf16 [N][K] ----------------
__global__ __launch_bounds__(256) void k_wt(const float* __restrict__ src, __bf16* __restrict__ dst,
                                            int srcN, int dstK, long sstride, long dstride, int drowoff) {
  __shared__ float t[32][33];
  int nt = blockIdx.x, kt = blockIdx.y, l = blockIdx.z;
  const float* s = src + (size_t)l * sstride;
  __bf16* d = dst + (size_t)l * dstride;
  int r = threadIdx.x >> 3, c4 = (threadIdx.x & 7) * 4;
  float4 v = *(const float4*)&s[(size_t)(kt*32 + r)*srcN + nt*32 + c4];
  t[r][c4+0]=v.x; t[r][c4+1]=v.y; t[r][c4+2]=v.z; t[r][c4+3]=v.w;
  __syncthreads();
  bf16x4v o = { (__bf16)t[c4+0][r], (__bf16)t[c4+1][r], (__bf16)t[c4+2][r], (__bf16)t[c4+3][r] };
  *(bf16x4v*)&d[(size_t)(drowoff + nt*32 + r)*dstK + kt*32 + c4] = o;
}

// ---------------- flat convert f32 -> bf16 (x4) ----------------
__global__ void k_cvt(const float* __restrict__ s, __bf16* __restrict__ d, int n4) {
  int i = blockIdx.x*256 + threadIdx.x;
  if (i >= n4) return;
  float4 v = ((const float4*)s)[i];
  bf16x4v o = { (__bf16)v.x, (__bf16)v.y, (__bf16)v.z, (__bf16)v.w };
  ((bf16x4v*)d)[i] = o;
}

// ---------------- V transpose: vb[4096][768] head-cols -> vtg[bn][64][512] ----------------
__global__ __launch_bounds__(256) void k_vt(const __bf16* __restrict__ vb, __bf16* __restrict__ vtg) {
  __shared__ __bf16 t[32][36];
  int it = blockIdx.x, dt = blockIdx.y, bn = blockIdx.z;
  int b = bn / 12, n = bn % 12;
  int r = threadIdx.x >> 3, c4 = (threadIdx.x & 7) * 4;
  bf16x4v v = *(const bf16x4v*)&vb[((size_t)(it*32 + r)*8 + b)*768 + n*64 + dt*32 + c4];
  t[r][c4+0]=v[0]; t[r][c4+1]=v[1]; t[r][c4+2]=v[2]; t[r][c4+3]=v[3];
  __syncthreads();
  bf16x4v o = { t[c4+0][r], t[c4+1][r], t[c4+2][r], t[c4+3][r] };
  *(bf16x4v*)&vtg[((size_t)bn*64 + dt*32 + r)*512 + it*32 + c4] = o;
}

// ---------------- MFMA GEMM (BK=64): C[M,N] = A[M,K] @ B^T, B is [N][K] bf16 ----------------
// ACT: 0 none, 1 exact GELU.  OUTM: 0 f32 (+z*cz), 1 bf16 (+z*cz), 2 QKV split
// SPLITK: 1 normal (z selects B/C slab), >1: z selects K-slice, partials to z*cz
template<int ACT, int OUTM, int SPLITK>
__global__ __launch_bounds__(256) void k_mgemm(
    const __bf16* __restrict__ A, const __bf16* __restrict__ B,
    const float* __restrict__ bias, void* __restrict__ Cv,
    __bf16* __restrict__ q1, __bf16* __restrict__ q2,
    __bf16* __restrict__ kk, __bf16* __restrict__ vv,
    const float* __restrict__ rwbp, const float* __restrict__ rrbp,
    int M, int N, int K, long bz, long cz) {
  __shared__ __align__(16) __bf16 As[128*64];   // 16 KB
  __shared__ __align__(16) __bf16 Bs[128*64];   // 16 KB
  int tid = threadIdx.x;
  int wave = tid >> 6, lane = tid & 63;
  int lr = lane & 15, lc = lane >> 4;
  int wm = wave >> 1, wn = wave & 1;
  int m0 = blockIdx.y * 128, n0 = blockIdx.x * 128;
  const __bf16* Bp = B + (SPLITK > 1 ? 0 : (size_t)blockIdx.z * bz);
  int kbeg = (SPLITK > 1) ? blockIdx.z * (K/SPLITK) : 0;
  int kend = (SPLITK > 1) ? kbeg + K/SPLITK : K;

  f32x4 acc[4][4];
  #pragma unroll
  for (int i = 0; i < 4; ++i)
    #pragma unroll
    for (int j = 0; j < 4; ++j) acc[i][j] = f32x4{0.f,0.f,0.f,0.f};

  // staging geometry: 8 chunks/row (128B rows), 4 chunk-groups per buffer
  int srow[4], scc[4];
  #pragma unroll
  for (int c = 0; c < 4; ++c) {
    int id = c*256 + tid;
    srow[c] = id >> 3;
    scc[c]  = (id & 7) ^ (srow[c] & 7);
  }

  for (int k0 = kbeg; k0 < kend; k0 += 64) {
    __syncthreads();
    #pragma unroll
    for (int c = 0; c < 4; ++c)
      gld16(A + (size_t)(m0 + srow[c])*K + k0 + scc[c]*8,
            (char*)As + c*4096 + wave*1024);
    #pragma unroll
    for (int c = 0; c < 4; ++c)
      gld16(Bp + (size_t)(n0 + srow[c])*K + k0 + scc[c]*8,
            (char*)Bs + c*4096 + wave*1024);
    __syncthreads();
    #pragma unroll
    for (int ks = 0; ks < 2; ++ks) {
      bf16x8 af[4], bfr[4];
      #pragma unroll
      for (int mi = 0; mi < 4; ++mi) {
        int row = wm*64 + mi*16 + lr;
        af[mi] = *(const bf16x8*)((const char*)As + row*128 + (((lc + ks*4) ^ (row & 7))*16));
      }
      #pragma unroll
      for (int ni = 0; ni < 4; ++ni) {
        int row = wn*64 + ni*16 + lr;
        bfr[ni] = *(const bf16x8*)((const char*)Bs + row*128 + (((lc + ks*4) ^ (row & 7))*16));
      }
      #pragma unroll
      for (int mi = 0; mi < 4; ++mi)
        #pragma unroll
        for (int ni = 0; ni < 4; ++ni)
          acc[mi][ni] = __builtin_amdgcn_mfma_f32_16x16x32_bf16(af[mi], bfr[ni], acc[mi][ni], 0, 0, 0);
    }
  }

  #pragma unroll
  for (int mi = 0; mi < 4; ++mi) {
    #pragma unroll
    for (int ni = 0; ni < 4; ++ni) {
      int gn = n0 + wn*64 + ni*16 + lr;
      float bv = (bias && (SPLITK == 1 || blockIdx.z == 0)) ? bias[gn] : 0.f;
      #pragma unroll
      for (int j = 0; j < 4; ++j) {
        int gm = m0 + wm*64 + mi*16 + lc*4 + j;
        float v = acc[mi][ni][j] + bv;
        if (ACT == 1) v = 0.5f*v*(1.0f + erff(v*0.70710678118654752f));
        if (OUTM == 0) {
          ((float*)Cv)[(size_t)blockIdx.z*cz + (size_t)gm*N + gn] = v;
        } else if (OUTM == 1) {
          ((__bf16*)Cv)[(size_t)blockIdx.z*cz + (size_t)gm*N + gn] = (__bf16)v;
        } else {
          if (gn < 768) {
            size_t o = (size_t)gm*768 + gn;
            q1[o] = (__bf16)(v + rwbp[gn]);
            q2[o] = (__bf16)(v + rrbp[gn]);
          } else if (gn < 1536) {
            kk[(size_t)gm*768 + gn - 768] = (__bf16)v;
          } else {
            vv[(size_t)gm*768 + gn - 1536] = (__bf16)v;
          }
        }
      }
    }
  }
}

// ---------------- fused flash attention: AC mfma + BD mfma (rel-shift) + softmax + PV ----------------
// grid (8 itiles of 64, 96 bn), block 256 (4 waves, 16 queries each)
// KR is a 128-row ring over the kr sliding window (64 new rows staged per j-tile)
__global__ __launch_bounds__(256) void k_pv(
    const __bf16* __restrict__ qrw, const __bf16* __restrict__ qrr,
    const __bf16* __restrict__ kb, const __bf16* __restrict__ vtg,
    const __bf16* __restrict__ krb, __bf16* __restrict__ vec) {
  // LDS: KT 8K @0 | VT 8K @8192 | KR 16K @16384 | BD 64x68 bf16 @32768 (8704) | P @41472 (2K/wave)
  __shared__ __align__(16) char lds[49664];
  int tid = threadIdx.x;
  int w = tid >> 6, lane = tid & 63;
  int lr = lane & 15, lg = lane >> 4;
  int bn = blockIdx.y;
  int b = bn / 12, n = bn % 12;
  int i0 = blockIdx.x * 64;
  char* KT = lds;
  char* VT = lds + 8192;
  char* KR = lds + 16384;
  char* BD = lds + 32768;
  char* Plds = lds + 41472 + w*2048;
  int base449 = 449 - i0;          // kr window origin (abs row of rel 0)

  // ---- prestage: Q tiles into KT/VT + full 128-row KR window (rel rows [0,128)) ----
  #pragma unroll
  for (int c = 0; c < 2; ++c) {
    int id = c*256 + tid;
    int row = id >> 3, cc = (id & 7) ^ (row & 7);
    gld16(qrw + ((size_t)(i0 + row)*8 + b)*768 + n*64 + cc*8, KT + c*4096 + w*1024);
    gld16(qrr + ((size_t)(i0 + row)*8 + b)*768 + n*64 + cc*8, VT + c*4096 + w*1024);
  }
  #pragma unroll
  for (int c = 0; c < 4; ++c) {
    int id = c*256 + tid;
    int row = id >> 3, cc = (id & 7) ^ (row & 7);
    gld16(krb + (size_t)(base449 + row)*768 + n*64 + cc*8, KR + c*4096 + w*1024);
  }
  __syncthreads();
  bf16x8 qwf[2], qrf[2];
  #pragma unroll
  for (int ks = 0; ks < 2; ++ks) {
    int row = w*16 + lr;
    qwf[ks] = *(const bf16x8*)(KT + row*128 + (((lg + ks*4) ^ (row & 7))*16));
    qrf[ks] = *(const bf16x8*)(VT + row*128 + (((lg + ks*4) ^ (row & 7))*16));
  }

  f32x4 O[4];
  #pragma unroll
  for (int d = 0; d < 4; ++d) O[d] = f32x4{0.f,0.f,0.f,0.f};
  float m_run = -1e30f, den = 0.f;

  for (int jt = 0; jt < 8; ++jt) {
    int j0 = jt * 64;
    __syncthreads();                    // prev tile consumed (and Q frags read on iter 0)
    // stage K [64][64], Vt [64][64]
    #pragma unroll
    for (int c = 0; c < 2; ++c) {
      int id = c*256 + tid;
      int row = id >> 3, cc = (id & 7) ^ (row & 7);
      gld16(kb + ((size_t)(j0 + row)*8 + b)*768 + n*64 + cc*8, KT + c*4096 + w*1024);
      gld16(vtg + ((size_t)bn*64 + row)*512 + j0 + cc*8, VT + c*4096 + w*1024);
    }
    // stage 64 NEW kr rows (rel [64*jt+64, 64*jt+128)) into ring slots
    if (jt) {
      int sb = (64*(jt+1)) & 127;       // 0 or 64
      #pragma unroll
      for (int c = 0; c < 2; ++c) {
        int id = c*256 + tid;
        int rw = id >> 3;               // 0..63
        int cc = (id & 7) ^ (rw & 7);   // slot&7 == rw&7 (sb multiple of 64)
        gld16(krb + (size_t)(base449 + 64*jt + 64 + rw)*768 + n*64 + cc*8,
              KR + sb*128 + c*4096 + w*1024);
      }
    }
    __syncthreads();

    __builtin_amdgcn_s_setprio(1);
    // ---- AC: mfma(K, Qw): lane holds q = lr, keys = ksub*16 + lg*4 + r ----
    f32x4 acf[4];
    #pragma unroll
    for (int ksub = 0; ksub < 4; ++ksub) acf[ksub] = f32x4{0.f,0.f,0.f,0.f};
    #pragma unroll
    for (int ks = 0; ks < 2; ++ks) {
      #pragma unroll
      for (int ksub = 0; ksub < 4; ++ksub) {
        int row = ksub*16 + lr;
        bf16x8 kf = *(const bf16x8*)(KT + row*128 + (((lg + ks*4) ^ (row & 7))*16));
        acf[ksub] = __builtin_amdgcn_mfma_f32_16x16x32_bf16(kf, qwf[ks], acf[ksub], 0, 0, 0);
      }
    }
    // ---- BD: mfma(Qr, KRwin). Only kt in [3-w, 7-w] yields in-band jloc for wave w ----
    int ktbase = 3 - w;
    #pragma unroll
    for (int t = 0; t < 5; ++t) {
      int kt = ktbase + t;
      f32x4 bda = f32x4{0.f,0.f,0.f,0.f};
      #pragma unroll
      for (int ks = 0; ks < 2; ++ks) {
        int rowk = kt*16 + lr;
        int s = (64*jt + rowk) & 127;   // ring slot; s&7 == rowk&7
        bf16x8 krf = *(const bf16x8*)(KR + s*128 + (((lg + ks*4) ^ (rowk & 7))*16));
        bda = __builtin_amdgcn_mfma_f32_16x16x32_bf16(qrf[ks], krf, bda, 0, 0, 0);
      }
      #pragma unroll
      for (int jreg = 0; jreg < 4; ++jreg) {
        int il = w*16 + lg*4 + jreg;              // i_local in [0,64)
        int jloc = kt*16 + lr + il - 63;
        if ((unsigned)jloc < 64u)
          *(__bf16*)(BD + (il*68 + jloc)*2) = (__bf16)bda[jreg];
      }
    }
    __builtin_amdgcn_s_setprio(0);

    // ---- softmax (lane owns query q = lr of wave w) ----
    float sc[4][4];
    float mt = -1e30f;
    int qrow = w*16 + lr;
    #pragma unroll
    for (int ksub = 0; ksub < 4; ++ksub) {
      bf16x4v bdv = *(const bf16x4v*)(BD + (qrow*68 + ksub*16 + lg*4)*2);
      #pragma unroll
      for (int r = 0; r < 4; ++r) {
        float s = (acf[ksub][r] + (float)bdv[r]) * SCALE;
        sc[ksub][r] = s;
        mt = fmaxf(mt, s);
      }
    }
    mt = fmaxf(mt, __shfl_xor(mt, 16));
    mt = fmaxf(mt, __shfl_xor(mt, 32));
    float m_new = fmaxf(m_run, mt);
    float f = __expf(m_run - m_new);
    m_run = m_new;
    float psum = 0.f;
    #pragma unroll
    for (int ksub = 0; ksub < 4; ++ksub) {
      bf16x4v pv;
      #pragma unroll
      for (int r = 0; r < 4; ++r) {
        float p = __expf(sc[ksub][r] - m_new);
        psum += p;
        pv[r] = (__bf16)p;
      }
      int k = ksub*16 + lg*4;
      *(bf16x4v*)(Plds + lr*128 + (((k >> 3) ^ (lr & 7))*16) + (k & 7)*2) = pv;
    }
    den = den*f + psum;
    float fv[4];
    #pragma unroll
    for (int j = 0; j < 4; ++j) fv[j] = __shfl(f, lg*4 + j);
    #pragma unroll
    for (int d = 0; d < 4; ++d)
      #pragma unroll
      for (int j = 0; j < 4; ++j) O[d][j] *= fv[j];
    // ---- PV: mfma(P, Vt): D[row=q][col=d] ----
    __builtin_amdgcn_s_setprio(1);
    #pragma unroll
    for (int ks = 0; ks < 2; ++ks) {
      bf16x8 paf = *(const bf16x8*)(Plds + lr*128 + (((lg + ks*4) ^ (lr & 7))*16));
      #pragma unroll
      for (int d = 0; d < 4; ++d) {
        int row = d*16 + lr;
        bf16x8 vf = *(const bf16x8*)(VT + row*128 + (((lg + ks*4) ^ (row & 7))*16));
        O[d] = __builtin_amdgcn_mfma_f32_16x16x32_bf16(paf, vf, O[d], 0, 0, 0);
      }
    }
    __builtin_amdgcn_s_setprio(0);
  }

  den += __shfl_xor(den, 16);
  den += __shfl_xor(den, 32);
  float inv = 1.0f / den;
  float iv[4];
  #pragma unroll
  for (int j = 0; j < 4; ++j) iv[j] = __shfl(inv, lg*4 + j);
  #pragma unroll
  for (int d = 0; d < 4; ++d) {
    #pragma unroll
    for (int j = 0; j < 4; ++j) {
      int qg = i0 + w*16 + lg*4 + j;
      int dd = d*16 + lr;
      vec[((size_t)qg*8 + b)*768 + n*64 + dd] = (__bf16)(O[d][j] * iv[j]);
    }
  }
}

// ---------------- head: summ = tanh(last[8][768] @ sumw + sumb) ----------------
__global__ __launch_bounds__(256) void k_head1(
    const float* __restrict__ last, const float* __restrict__ sumw,
    const float* __restrict__ sumb, float* __restrict__ summ) {
  __shared__ float red[256];
  int tid = threadIdx.x;
  int nn = blockIdx.x*16 + (tid & 15);
  int r = (tid >> 4) & 7;
  int half = tid >> 7;
  const float* lp = last + (size_t)r*768 + half*384;
  const float* wp = sumw + (size_t)half*384*768 + nn;
  float s = 0.f;
  #pragma unroll 4
  for (int k = 0; k < 384; ++k) s += lp[k] * wp[(size_t)k*768];
  red[tid] = s;
  __syncthreads();
  if (tid < 128) {
    float t = red[tid] + red[tid + 128];
    summ[(size_t)r*768 + nn] = tanhf(t + sumb[nn]);
  }
}

// ---------------- head: out = summ[8][768] @ pjw[768][2] + pjb ----------------
__global__ __launch_bounds__(128) void k_head2(
    const float* __restrict__ summ, const float* __restrict__ pjw,
    const float* __restrict__ pjb, float* __restrict__ out) {
  __shared__ float red[128];
  int tid = threadIdx.x;
  int o = tid & 15;           // output index: r = o>>1, c = o&1
  int r = o >> 1, c = o & 1;
  int seg = tid >> 4;         // 8 segments of 96
  float s = 0.f;
  #pragma unroll 4
  for (int k = seg*96; k < seg*96 + 96; ++k) s += summ[(size_t)r*768 + k] * pjw[(size_t)k*2 + c];
  red[tid] = s;
  __syncthreads();
  if (tid < 16) {
    float t = 0.f;
    #pragma unroll
    for (int sg = 0; sg < 8; ++sg) t += red[sg*16 + tid];
    out[tid] = t + pjb[tid & 1];
  }
}

// ---------------- LayerNorm(x [+ x2] + res) -> out fp32 + bf16 (192 thr, float4) ----------------
template<int HASX2>
__global__ __launch_bounds__(192) void k_ln_res(
    const float* __restrict__ x, const float* __restrict__ x2,
    const float* __restrict__ res, const float* __restrict__ g,
    const float* __restrict__ bta, float* __restrict__ out, __bf16* __restrict__ outb) {
  __shared__ float red[6];
  int row = blockIdx.x, tid = threadIdx.x;
  size_t off = (size_t)row*768 + tid*4;
  float4 v = *(const float4*)(x + off);
  if (HASX2) {
    float4 u = *(const float4*)(x2 + off);
    v.x += u.x; v.y += u.y; v.z += u.z; v.w += u.w;
  }
  {
    float4 u = *(const float4*)(res + off);
    v.x += u.x; v.y += u.y; v.z += u.z; v.w += u.w;
  }
  float s = v.x + v.y + v.z + v.w;
  #pragma unroll
  for (int o = 32; o; o >>= 1) s += __shfl_down(s, o, 64);
  if ((tid & 63) == 0) red[tid >> 6] = s;
  __syncthreads();
  float mean = (red[0] + red[1] + red[2]) * (1.0f/768.0f);
  float a0 = v.x - mean, a1 = v.y - mean, a2 = v.z - mean, a3 = v.w - mean;
  float vs = a0*a0 + a1*a1 + a2*a2 + a3*a3;
  #pragma unroll
  for (int o = 32; o; o >>= 1) vs += __shfl_down(vs, o, 64);
  if ((tid & 63) == 0) red[3 + (tid >> 6)] = vs;
  __syncthreads();
  float var = (red[3] + red[4] + red[5]) * (1.0f/768.0f);
  float rstd = 1.0f / sqrtf(var + 1e-12f);
  float4 gv = *(const float4*)(g + tid*4);
  float4 bv = *(const float4*)(bta + tid*4);
  float4 y;
  y.x = a0*rstd*gv.x + bv.x;
  y.y = a1*rstd*gv.y + bv.y;
  y.z = a2*rstd*gv.z + bv.z;
  y.w = a3*rstd*gv.w + bv.w;
  *(float4*)(out + off) = y;
  bf16x4v yb = { (__bf16)y.x, (__bf16)y.y, (__bf16)y.z, (__bf16)y.w };
  *(bf16x4v*)(outb + off) = yb;
}

extern "C" void kernel_launch(void* const* d_in, const int* in_sizes, int n_in,
                              void* d_out, int out_size, void* d_ws, size_t ws_size,
                              hipStream_t stream) {
  (void)in_sizes; (void)n_in; (void)out_size; (void)ws_size;
  const int*   tox  = (const int*)d_in[0];
  const float* emb  = (const float*)d_in[3];
  const float* q_w  = (const float*)d_in[4];
  const float* k_w  = (const float*)d_in[5];
  const float* v_w  = (const float*)d_in[6];
  const float* o_w  = (const float*)d_in[7];
  const float* r_w  = (const float*)d_in[8];
  const float* rwb  = (const float*)d_in[9];
  const float* rrb  = (const float*)d_in[10];
  const float* ln1g = (const float*)d_in[11];
  const float* ln1b = (const float*)d_in[12];
  const float* fw1  = (const float*)d_in[13];
  const float* fb1  = (const float*)d_in[14];
  const float* fw2  = (const float*)d_in[15];
  const float* fb2  = (const float*)d_in[16];
  const float* ln2g = (const float*)d_in[17];
  const float* ln2b = (const float*)d_in[18];
  const float* sumw = (const float*)d_in[19];
  const float* sumb = (const float*)d_in[20];
  const float* pjw  = (const float*)d_in[21];
  const float* pjb  = (const float*)d_in[22];
  float* out = (float*)d_out;

  // ---- workspace bump allocator (256B aligned), ~287 MB total ----
  char* wsp = (char*)d_ws;
  auto alloc = [&](size_t bytes) { char* rp = wsp; wsp += (bytes + 255) & ~(size_t)255; return rp; };
  __bf16* qkvw   = (__bf16*)alloc((size_t)LAYERS*2304*768*2);
  __bf16* rwt    = (__bf16*)alloc((size_t)LAYERS*768*768*2);
  __bf16* owb    = (__bf16*)alloc((size_t)LAYERS*768*768*2);
  __bf16* ff1t   = (__bf16*)alloc((size_t)LAYERS*768*3072*2);
  __bf16* ff2t   = (__bf16*)alloc((size_t)LAYERS*3072*768*2);
  float*  h      = (float*) alloc((size_t)NTOK*DMODEL*4);
  __bf16* h_bf   = (__bf16*)alloc((size_t)NTOK*DMODEL*2);
  __bf16* r_bf   = (__bf16*)alloc((size_t)KLEN*DMODEL*2);
  __bf16* krb    = (__bf16*)alloc(((size_t)LAYERS*KLEN + 8)*DMODEL*2);  // +pad rows (window overreach)
  __bf16* vtg    = (__bf16*)alloc((size_t)96*64*512*2);
  __bf16* vec_bf = (__bf16*)alloc((size_t)NTOK*DMODEL*2);
  float*  A5     = (float*) alloc((size_t)2*NTOK*DMODEL*4);   // two split-K halves, contiguous
  float*  summ   = (float*) alloc((size_t)BATCH*DMODEL*4);
  // union region (25.17 MB): qrw|qrr|kbuf|vb, aliased by mid_bf (dead by FF1 time)
  char*   U      = alloc((size_t)NTOK*DMODEL*2 * 4);
  __bf16* qrw    = (__bf16*)U;
  __bf16* qrr    = (__bf16*)(U + (size_t)NTOK*DMODEL*2);
  __bf16* kbuf   = (__bf16*)(U + (size_t)NTOK*DMODEL*2*2);
  __bf16* vb     = (__bf16*)(U + (size_t)NTOK*DMODEL*2*3);
  __bf16* mid_bf = (__bf16*)U;

  dim3 b256(256);
  // ---- weight convert/transpose ----
  k_wt<<<dim3(24,24,LAYERS), b256, 0, stream>>>(q_w, qkvw, 768, 768, 589824, 2304*768, 0);
  k_wt<<<dim3(24,24,LAYERS), b256, 0, stream>>>(k_w, qkvw, 768, 768, 589824, 2304*768, 768);
  k_wt<<<dim3(24,24,LAYERS), b256, 0, stream>>>(v_w, qkvw, 768, 768, 589824, 2304*768, 1536);
  k_wt<<<dim3(24,24,LAYERS), b256, 0, stream>>>(r_w, rwt, 768, 768, 589824, 589824, 0);
  k_wt<<<dim3(96,24,LAYERS), b256, 0, stream>>>(fw1, ff1t, 3072, 768, (long)768*3072, (long)3072*768, 0);
  k_wt<<<dim3(24,96,LAYERS), b256, 0, stream>>>(fw2, ff2t, 768, 3072, (long)3072*768, (long)768*3072, 0);
  k_cvt<<<(LAYERS*589824/4 + 255)/256, b256, 0, stream>>>(o_w, owb, LAYERS*589824/4);

  k_embed<<<NTOK, b256, 0, stream>>>(tox, emb, h, h_bf);
  k_posenc<<<(KLEN*DMODEL + 255)/256, b256, 0, stream>>>(r_bf);

  // kr for ALL layers in one dispatch: [L][1024][768] bf16
  k_mgemm<0,1,1><<<dim3(6,8,LAYERS), b256, 0, stream>>>(r_bf, rwt, nullptr, krb,
      nullptr, nullptr, nullptr, nullptr, nullptr, nullptr,
      KLEN, 768, 768, (long)589824, (long)KLEN*DMODEL);

  for (int l = 0; l < LAYERS; ++l) {
    // QKV fused (writes qrw/qrr with biases, kbuf, vb)
    k_mgemm<0,2,1><<<dim3(18,32), b256, 0, stream>>>(h_bf, qkvw + (size_t)l*2304*768, nullptr, nullptr,
        qrw, qrr, kbuf, vb, rwb + l*DMODEL, rrb + l*DMODEL, NTOK, 2304, 768, 0, 0);
    // V transpose to [bn][64][512]
    k_vt<<<dim3(16,2,96), b256, 0, stream>>>(vb, vtg);
    // fused attention (AC + BD + softmax + PV)
    k_pv<<<dim3(8,96), b256, 0, stream>>>(qrw, qrr, kbuf, vtg,
        krb + (size_t)l*KLEN*DMODEL, vec_bf);
    // O projection
    k_mgemm<0,0,1><<<dim3(6,32), b256, 0, stream>>>(vec_bf, owb + (size_t)l*589824, nullptr, A5,
        nullptr, nullptr, nullptr, nullptr, nullptr, nullptr, NTOK, 768, 768, 0, 0);
    k_ln_res<0><<<NTOK, dim3(192), 0, stream>>>(A5, nullptr, h, ln1g + l*DMODEL, ln1b + l*DMODEL, h, h_bf);
    // FF
    k_mgemm<1,1,1><<<dim3(24,32), b256, 0, stream>>>(h_bf, ff1t + (size_t)l*768*3072, fb1 + (size_t)l*DFF, mid_bf,
        nullptr, nullptr, nullptr, nullptr, nullptr, nullptr, NTOK, DFF, 768, 0, 0);
    k_mgemm<0,0,2><<<dim3(6,32,2), b256, 0, stream>>>(mid_bf, ff2t + (size_t)l*3072*768, fb2 + l*DMODEL, A5,
        nullptr, nullptr, nullptr, nullptr, nullptr, nullptr, NTOK, 768, DFF, 0, (long)NTOK*DMODEL);
    k_ln_res<1><<<NTOK, dim3(192), 0, stream>>>(A5, A5 + (size_t)NTOK*DMODEL, h,
        ln2g + l*DMODEL, ln2b + l*DMODEL, h, h_bf);
  }

  const float* lastp = h + (size_t)(NTOK - BATCH)*DMODEL;
  k_head1<<<dim3(48), b256, 0, stream>>>(lastp, sumw, sumb, summ);
  k_head2<<<dim3(1), dim3(128), 0, stream>>>(summ, pjw, pjb, out);
}

// Round 6
// 2261.768 us; speedup vs baseline: 12.8660x; 1.0350x over previous
//
#include <hip/hip_runtime.h>
#include <math.h>
#include <stdint.h>

#define LAYERS 12
#define DMODEL 768
#define NHEAD 12
#define DHEAD 64
#define DFF 3072
#define BATCH 8
#define SEQ 512
#define NTOK (BATCH*SEQ)   /* 4096 */
#define KLEN 1024
#define SCALE 0.125f       /* 1/sqrt(64) */

typedef __bf16 bf16x8 __attribute__((ext_vector_type(8)));
typedef __bf16 bf16x4v __attribute__((ext_vector_type(4)));
typedef float f32x4 __attribute__((ext_vector_type(4)));

__device__ __forceinline__ void gld16(const void* g, void* l) {
  auto gp = reinterpret_cast<const __attribute__((address_space(1))) void*>(
      reinterpret_cast<uintptr_t>(g));
  auto lp = reinterpret_cast<__attribute__((address_space(3))) void*>(
      reinterpret_cast<uintptr_t>(l));
  __builtin_amdgcn_global_load_lds(gp, lp, 16, 0, 0);
}

// ---------------- embedding gather ----------------
__global__ void k_embed(const int* __restrict__ tox, const float* __restrict__ emb,
                        float* __restrict__ h, __bf16* __restrict__ hb) {
  int n = blockIdx.x;            // n = i*BATCH + b
  int i = n >> 3, b = n & 7;
  int tok = tox[b*SEQ + i];
  const float* src = emb + (size_t)tok * DMODEL;
  size_t off = (size_t)n * DMODEL;
  for (int d = threadIdx.x; d < DMODEL; d += blockDim.x) {
    float v = src[d];
    h[off+d] = v; hb[off+d] = (__bf16)v;
  }
}

// ---------------- positional encoding (bf16, GEMM input only) ----------------
__global__ void k_posenc(__bf16* __restrict__ r) {
  int idx = blockIdx.x * blockDim.x + threadIdx.x;
  if (idx >= KLEN * DMODEL) return;
  int k = idx / DMODEL, d = idx % DMODEL;
  float pos = (float)(SEQ - k);
  int j = (d < 384) ? d : d - 384;
  float invf = powf(10000.0f, -(2.0f * (float)j) / 768.0f);
  float a = pos * invf;
  r[idx] = (__bf16)((d < 384) ? sinf(a) : cosf(a));
}

// ---------------- weight transpose+convert: f32 [K][N] -> bf16 [N][K] ----------------
__global__ __launch_bounds__(256) void k_wt(const float* __restrict__ src, __bf16* __restrict__ dst,
                                            int srcN, int dstK, long sstride, long dstride, int drowoff) {
  __shared__ float t[32][33];
  int nt = blockIdx.x, kt = blockIdx.y, l = blockIdx.z;
  const float* s = src + (size_t)l * sstride;
  __bf16* d = dst + (size_t)l * dstride;
  int r = threadIdx.x >> 3, c4 = (threadIdx.x & 7) * 4;
  float4 v = *(const float4*)&s[(size_t)(kt*32 + r)*srcN + nt*32 + c4];
  t[r][c4+0]=v.x; t[r][c4+1]=v.y; t[r][c4+2]=v.z; t[r][c4+3]=v.w;
  __syncthreads();
  bf16x4v o = { (__bf16)t[c4+0][r], (__bf16)t[c4+1][r], (__bf16)t[c4+2][r], (__bf16)t[c4+3][r] };
  *(bf16x4v*)&d[(size_t)(drowoff + nt*32 + r)*dstK + kt*32 + c4] = o;
}

// ---------------- flat convert f32 -> bf16 (x4) ----------------
__global__ void k_cvt(const float* __restrict__ s, __bf16* __restrict__ d, int n4) {
  int i = blockIdx.x*256 + threadIdx.x;
  if (i >= n4) return;
  float4 v = ((const float4*)s)[i];
  bf16x4v o = { (__bf16)v.x, (__bf16)v.y, (__bf16)v.z, (__bf16)v.w };
  ((bf16x4v*)d)[i] = o;
}

// ---------------- V transpose: vb[4096][768] head-cols -> vtg[bn][64][512] ----------------
__global__ __launch_bounds__(256) void k_vt(const __bf16* __restrict__ vb, __bf16* __restrict__ vtg) {
  __shared__ __bf16 t[32][36];
  int it = blockIdx.x, dt = blockIdx.y, bn = blockIdx.z;
  int b = bn / 12, n = bn % 12;
  int r = threadIdx.x >> 3, c4 = (threadIdx.x & 7) * 4;
  bf16x4v v = *(const bf16x4v*)&vb[((size_t)(it*32 + r)*8 + b)*768 + n*64 + dt*32 + c4];
  t[r][c4+0]=v[0]; t[r][c4+1]=v[1]; t[r][c4+2]=v[2]; t[r][c4+3]=v[3];
  __syncthreads();
  bf16x4v o = { t[c4+0][r], t[c4+1][r], t[c4+2][r], t[c4+3][r] };
  *(bf16x4v*)&vtg[((size_t)bn*64 + dt*32 + r)*512 + it*32 + c4] = o;
}

// ---------------- MFMA GEMM (BK=64): C[M,N] = A[M,K] @ B^T, B is [N][K] bf16 ----------------
// ACT: 0 none, 1 exact GELU.  OUTM: 0 f32 (+z*cz), 1 bf16 (+z*cz), 2 QKV split
// SPLITK: 1 normal (z selects B/C slab), >1: z selects K-slice, partials to z*cz
template<int ACT, int OUTM, int SPLITK>
__global__ __launch_bounds__(256) void k_mgemm(
    const __bf16* __restrict__ A, const __bf16* __restrict__ B,
    const float* __restrict__ bias, void* __restrict__ Cv,
    __bf16* __restrict__ q1, __bf16* __restrict__ q2,
    __bf16* __restrict__ kk, __bf16* __restrict__ vv,
    const float* __restrict__ rwbp, const float* __restrict__ rrbp,
    int M, int N, int K, long bz, long cz) {
  __shared__ __align__(16) __bf16 As[128*64];   // 16 KB
  __shared__ __align__(16) __bf16 Bs[128*64];   // 16 KB
  int tid = threadIdx.x;
  int wave = tid >> 6, lane = tid & 63;
  int lr = lane & 15, lc = lane >> 4;
  int wm = wave >> 1, wn = wave & 1;
  int m0 = blockIdx.y * 128, n0 = blockIdx.x * 128;
  const __bf16* Bp = B + (SPLITK > 1 ? 0 : (size_t)blockIdx.z * bz);
  int kbeg = (SPLITK > 1) ? blockIdx.z * (K/SPLITK) : 0;
  int kend = (SPLITK > 1) ? kbeg + K/SPLITK : K;

  f32x4 acc[4][4];
  #pragma unroll
  for (int i = 0; i < 4; ++i)
    #pragma unroll
    for (int j = 0; j < 4; ++j) acc[i][j] = f32x4{0.f,0.f,0.f,0.f};

  // staging geometry: 8 chunks/row (128B rows), 4 chunk-groups per buffer
  int srow[4], scc[4];
  #pragma unroll
  for (int c = 0; c < 4; ++c) {
    int id = c*256 + tid;
    srow[c] = id >> 3;
    scc[c]  = (id & 7) ^ (srow[c] & 7);
  }

  for (int k0 = kbeg; k0 < kend; k0 += 64) {
    __syncthreads();
    #pragma unroll
    for (int c = 0; c < 4; ++c)
      gld16(A + (size_t)(m0 + srow[c])*K + k0 + scc[c]*8,
            (char*)As + c*4096 + wave*1024);
    #pragma unroll
    for (int c = 0; c < 4; ++c)
      gld16(Bp + (size_t)(n0 + srow[c])*K + k0 + scc[c]*8,
            (char*)Bs + c*4096 + wave*1024);
    __syncthreads();
    #pragma unroll
    for (int ks = 0; ks < 2; ++ks) {
      bf16x8 af[4], bfr[4];
      #pragma unroll
      for (int mi = 0; mi < 4; ++mi) {
        int row = wm*64 + mi*16 + lr;
        af[mi] = *(const bf16x8*)((const char*)As + row*128 + (((lc + ks*4) ^ (row & 7))*16));
      }
      #pragma unroll
      for (int ni = 0; ni < 4; ++ni) {
        int row = wn*64 + ni*16 + lr;
        bfr[ni] = *(const bf16x8*)((const char*)Bs + row*128 + (((lc + ks*4) ^ (row & 7))*16));
      }
      #pragma unroll
      for (int mi = 0; mi < 4; ++mi)
        #pragma unroll
        for (int ni = 0; ni < 4; ++ni)
          acc[mi][ni] = __builtin_amdgcn_mfma_f32_16x16x32_bf16(af[mi], bfr[ni], acc[mi][ni], 0, 0, 0);
    }
  }

  #pragma unroll
  for (int mi = 0; mi < 4; ++mi) {
    #pragma unroll
    for (int ni = 0; ni < 4; ++ni) {
      int gn = n0 + wn*64 + ni*16 + lr;
      float bv = (bias && (SPLITK == 1 || blockIdx.z == 0)) ? bias[gn] : 0.f;
      #pragma unroll
      for (int j = 0; j < 4; ++j) {
        int gm = m0 + wm*64 + mi*16 + lc*4 + j;
        float v = acc[mi][ni][j] + bv;
        if (ACT == 1) v = 0.5f*v*(1.0f + erff(v*0.70710678118654752f));
        if (OUTM == 0) {
          ((float*)Cv)[(size_t)blockIdx.z*cz + (size_t)gm*N + gn] = v;
        } else if (OUTM == 1) {
          ((__bf16*)Cv)[(size_t)blockIdx.z*cz + (size_t)gm*N + gn] = (__bf16)v;
        } else {
          if (gn < 768) {
            size_t o = (size_t)gm*768 + gn;
            q1[o] = (__bf16)(v + rwbp[gn]);
            q2[o] = (__bf16)(v + rrbp[gn]);
          } else if (gn < 1536) {
            kk[(size_t)gm*768 + gn - 768] = (__bf16)v;
          } else {
            vv[(size_t)gm*768 + gn - 1536] = (__bf16)v;
          }
        }
      }
    }
  }
}

// ---------------- fused flash attention: AC mfma + BD mfma (rel-shift) + softmax + PV ----------------
// grid (8 itiles of 64, 96 bn), block 256 (4 waves, 16 queries each)
// KR is a 128-row ring over the kr sliding window (64 new rows staged per j-tile)
__global__ __launch_bounds__(256) void k_pv(
    const __bf16* __restrict__ qrw, const __bf16* __restrict__ qrr,
    const __bf16* __restrict__ kb, const __bf16* __restrict__ vtg,
    const __bf16* __restrict__ krb, __bf16* __restrict__ vec) {
  // LDS: KT 8K @0 | VT 8K @8192 | KR 16K @16384 | BD 64x68 bf16 @32768 (8704) | P @41472 (2K/wave)
  __shared__ __align__(16) char lds[49664];
  int tid = threadIdx.x;
  int w = tid >> 6, lane = tid & 63;
  int lr = lane & 15, lg = lane >> 4;
  int bn = blockIdx.y;
  int b = bn / 12, n = bn % 12;
  int i0 = blockIdx.x * 64;
  char* KT = lds;
  char* VT = lds + 8192;
  char* KR = lds + 16384;
  char* BD = lds + 32768;
  char* Plds = lds + 41472 + w*2048;
  int base449 = 449 - i0;          // kr window origin (abs row of rel 0)

  // ---- prestage: Q tiles into KT/VT + full 128-row KR window (rel rows [0,128)) ----
  #pragma unroll
  for (int c = 0; c < 2; ++c) {
    int id = c*256 + tid;
    int row = id >> 3, cc = (id & 7) ^ (row & 7);
    gld16(qrw + ((size_t)(i0 + row)*8 + b)*768 + n*64 + cc*8, KT + c*4096 + w*1024);
    gld16(qrr + ((size_t)(i0 + row)*8 + b)*768 + n*64 + cc*8, VT + c*4096 + w*1024);
  }
  #pragma unroll
  for (int c = 0; c < 4; ++c) {
    int id = c*256 + tid;
    int row = id >> 3, cc = (id & 7) ^ (row & 7);
    gld16(krb + (size_t)(base449 + row)*768 + n*64 + cc*8, KR + c*4096 + w*1024);
  }
  __syncthreads();
  bf16x8 qwf[2], qrf[2];
  #pragma unroll
  for (int ks = 0; ks < 2; ++ks) {
    int row = w*16 + lr;
    qwf[ks] = *(const bf16x8*)(KT + row*128 + (((lg + ks*4) ^ (row & 7))*16));
    qrf[ks] = *(const bf16x8*)(VT + row*128 + (((lg + ks*4) ^ (row & 7))*16));
  }

  f32x4 O[4];
  #pragma unroll
  for (int d = 0; d < 4; ++d) O[d] = f32x4{0.f,0.f,0.f,0.f};
  float m_run = -1e30f, den = 0.f;

  for (int jt = 0; jt < 8; ++jt) {
    int j0 = jt * 64;
    __syncthreads();                    // prev tile consumed (and Q frags read on iter 0)
    // stage K [64][64], Vt [64][64]
    #pragma unroll
    for (int c = 0; c < 2; ++c) {
      int id = c*256 + tid;
      int row = id >> 3, cc = (id & 7) ^ (row & 7);
      gld16(kb + ((size_t)(j0 + row)*8 + b)*768 + n*64 + cc*8, KT + c*4096 + w*1024);
      gld16(vtg + ((size_t)bn*64 + row)*512 + j0 + cc*8, VT + c*4096 + w*1024);
    }
    // stage 64 NEW kr rows (rel [64*jt+64, 64*jt+128)) into ring slots
    if (jt) {
      int sb = (64*(jt+1)) & 127;       // 0 or 64
      #pragma unroll
      for (int c = 0; c < 2; ++c) {
        int id = c*256 + tid;
        int rw = id >> 3;               // 0..63
        int cc = (id & 7) ^ (rw & 7);   // slot&7 == rw&7 (sb multiple of 64)
        gld16(krb + (size_t)(base449 + 64*jt + 64 + rw)*768 + n*64 + cc*8,
              KR + sb*128 + c*4096 + w*1024);
      }
    }
    __syncthreads();

    __builtin_amdgcn_s_setprio(1);
    // ---- AC: mfma(K, Qw): lane holds q = lr, keys = ksub*16 + lg*4 + r ----
    f32x4 acf[4];
    #pragma unroll
    for (int ksub = 0; ksub < 4; ++ksub) acf[ksub] = f32x4{0.f,0.f,0.f,0.f};
    #pragma unroll
    for (int ks = 0; ks < 2; ++ks) {
      #pragma unroll
      for (int ksub = 0; ksub < 4; ++ksub) {
        int row = ksub*16 + lr;
        bf16x8 kf = *(const bf16x8*)(KT + row*128 + (((lg + ks*4) ^ (row & 7))*16));
        acf[ksub] = __builtin_amdgcn_mfma_f32_16x16x32_bf16(kf, qwf[ks], acf[ksub], 0, 0, 0);
      }
    }
    // ---- BD: mfma(Qr, KRwin). Only kt in [3-w, 7-w] yields in-band jloc for wave w ----
    int ktbase = 3 - w;
    #pragma unroll
    for (int t = 0; t < 5; ++t) {
      int kt = ktbase + t;
      f32x4 bda = f32x4{0.f,0.f,0.f,0.f};
      #pragma unroll
      for (int ks = 0; ks < 2; ++ks) {
        int rowk = kt*16 + lr;
        int s = (64*jt + rowk) & 127;   // ring slot; s&7 == rowk&7
        bf16x8 krf = *(const bf16x8*)(KR + s*128 + (((lg + ks*4) ^ (rowk & 7))*16));
        bda = __builtin_amdgcn_mfma_f32_16x16x32_bf16(qrf[ks], krf, bda, 0, 0, 0);
      }
      #pragma unroll
      for (int jreg = 0; jreg < 4; ++jreg) {
        int il = w*16 + lg*4 + jreg;              // i_local in [0,64)
        int jloc = kt*16 + lr + il - 63;
        if ((unsigned)jloc < 64u)
          *(__bf16*)(BD + (il*68 + jloc)*2) = (__bf16)bda[jreg];
      }
    }
    __builtin_amdgcn_s_setprio(0);

    // ---- softmax (lane owns query q = lr of wave w) ----
    float sc[4][4];
    float mt = -1e30f;
    int qrow = w*16 + lr;
    #pragma unroll
    for (int ksub = 0; ksub < 4; ++ksub) {
      bf16x4v bdv = *(const bf16x4v*)(BD + (qrow*68 + ksub*16 + lg*4)*2);
      #pragma unroll
      for (int r = 0; r < 4; ++r) {
        float s = (acf[ksub][r] + (float)bdv[r]) * SCALE;
        sc[ksub][r] = s;
        mt = fmaxf(mt, s);
      }
    }
    mt = fmaxf(mt, __shfl_xor(mt, 16));
    mt = fmaxf(mt, __shfl_xor(mt, 32));
    float m_new = fmaxf(m_run, mt);
    float f = __expf(m_run - m_new);
    m_run = m_new;
    float psum = 0.f;
    #pragma unroll
    for (int ksub = 0; ksub < 4; ++ksub) {
      bf16x4v pv;
      #pragma unroll
      for (int r = 0; r < 4; ++r) {
        float p = __expf(sc[ksub][r] - m_new);
        psum += p;
        pv[r] = (__bf16)p;
      }
      int k = ksub*16 + lg*4;
      *(bf16x4v*)(Plds + lr*128 + (((k >> 3) ^ (lr & 7))*16) + (k & 7)*2) = pv;
    }
    den = den*f + psum;
    float fv[4];
    #pragma unroll
    for (int j = 0; j < 4; ++j) fv[j] = __shfl(f, lg*4 + j);
    #pragma unroll
    for (int d = 0; d < 4; ++d)
      #pragma unroll
      for (int j = 0; j < 4; ++j) O[d][j] *= fv[j];
    // ---- PV: mfma(P, Vt): D[row=q][col=d] ----
    __builtin_amdgcn_s_setprio(1);
    #pragma unroll
    for (int ks = 0; ks < 2; ++ks) {
      bf16x8 paf = *(const bf16x8*)(Plds + lr*128 + (((lg + ks*4) ^ (lr & 7))*16));
      #pragma unroll
      for (int d = 0; d < 4; ++d) {
        int row = d*16 + lr;
        bf16x8 vf = *(const bf16x8*)(VT + row*128 + (((lg + ks*4) ^ (row & 7))*16));
        O[d] = __builtin_amdgcn_mfma_f32_16x16x32_bf16(paf, vf, O[d], 0, 0, 0);
      }
    }
    __builtin_amdgcn_s_setprio(0);
  }

  den += __shfl_xor(den, 16);
  den += __shfl_xor(den, 32);
  float inv = 1.0f / den;
  float iv[4];
  #pragma unroll
  for (int j = 0; j < 4; ++j) iv[j] = __shfl(inv, lg*4 + j);
  #pragma unroll
  for (int d = 0; d < 4; ++d) {
    #pragma unroll
    for (int j = 0; j < 4; ++j) {
      int qg = i0 + w*16 + lg*4 + j;
      int dd = d*16 + lr;
      vec[((size_t)qg*8 + b)*768 + n*64 + dd] = (__bf16)(O[d][j] * iv[j]);
    }
  }
}

// ---------------- head: summ = tanh(last[8][768] @ sumw + sumb) ----------------
__global__ __launch_bounds__(256) void k_head1(
    const float* __restrict__ last, const float* __restrict__ sumw,
    const float* __restrict__ sumb, float* __restrict__ summ) {
  __shared__ float red[256];
  int tid = threadIdx.x;
  int nn = blockIdx.x*16 + (tid & 15);
  int r = (tid >> 4) & 7;
  int half = tid >> 7;
  const float* lp = last + (size_t)r*768 + half*384;
  const float* wp = sumw + (size_t)half*384*768 + nn;
  float s = 0.f;
  #pragma unroll 4
  for (int k = 0; k < 384; ++k) s += lp[k] * wp[(size_t)k*768];
  red[tid] = s;
  __syncthreads();
  if (tid < 128) {
    float t = red[tid] + red[tid + 128];
    summ[(size_t)r*768 + nn] = tanhf(t + sumb[nn]);
  }
}

// ---------------- head: out = summ[8][768] @ pjw[768][2] + pjb ----------------
__global__ __launch_bounds__(128) void k_head2(
    const float* __restrict__ summ, const float* __restrict__ pjw,
    const float* __restrict__ pjb, float* __restrict__ out) {
  __shared__ float red[128];
  int tid = threadIdx.x;
  int o = tid & 15;           // output index: r = o>>1, c = o&1
  int r = o >> 1, c = o & 1;
  int seg = tid >> 4;         // 8 segments of 96
  float s = 0.f;
  #pragma unroll 4
  for (int k = seg*96; k < seg*96 + 96; ++k) s += summ[(size_t)r*768 + k] * pjw[(size_t)k*2 + c];
  red[tid] = s;
  __syncthreads();
  if (tid < 16) {
    float t = 0.f;
    #pragma unroll
    for (int sg = 0; sg < 8; ++sg) t += red[sg*16 + tid];
    out[tid] = t + pjb[tid & 1];
  }
}

// ---------------- LayerNorm(sum of PARTS slabs + res) -> out fp32 + bf16 ----------------
template<int PARTS>
__global__ __launch_bounds__(192) void k_ln_res(
    const float* __restrict__ x, const float* __restrict__ res,
    const float* __restrict__ g, const float* __restrict__ bta,
    float* __restrict__ out, __bf16* __restrict__ outb) {
  __shared__ float red[6];
  int row = blockIdx.x, tid = threadIdx.x;
  size_t off = (size_t)row*768 + tid*4;
  float4 v = *(const float4*)(x + off);
  #pragma unroll
  for (int p = 1; p < PARTS; ++p) {
    float4 u = *(const float4*)(x + (size_t)p*NTOK*DMODEL + off);
    v.x += u.x; v.y += u.y; v.z += u.z; v.w += u.w;
  }
  {
    float4 u = *(const float4*)(res + off);
    v.x += u.x; v.y += u.y; v.z += u.z; v.w += u.w;
  }
  float s = v.x + v.y + v.z + v.w;
  #pragma unroll
  for (int o = 32; o; o >>= 1) s += __shfl_down(s, o, 64);
  if ((tid & 63) == 0) red[tid >> 6] = s;
  __syncthreads();
  float mean = (red[0] + red[1] + red[2]) * (1.0f/768.0f);
  float a0 = v.x - mean, a1 = v.y - mean, a2 = v.z - mean, a3 = v.w - mean;
  float vs = a0*a0 + a1*a1 + a2*a2 + a3*a3;
  #pragma unroll
  for (int o = 32; o; o >>= 1) vs += __shfl_down(vs, o, 64);
  if ((tid & 63) == 0) red[3 + (tid >> 6)] = vs;
  __syncthreads();
  float var = (red[3] + red[4] + red[5]) * (1.0f/768.0f);
  float rstd = 1.0f / sqrtf(var + 1e-12f);
  float4 gv = *(const float4*)(g + tid*4);
  float4 bv = *(const float4*)(bta + tid*4);
  float4 y;
  y.x = a0*rstd*gv.x + bv.x;
  y.y = a1*rstd*gv.y + bv.y;
  y.z = a2*rstd*gv.z + bv.z;
  y.w = a3*rstd*gv.w + bv.w;
  *(float4*)(out + off) = y;
  bf16x4v yb = { (__bf16)y.x, (__bf16)y.y, (__bf16)y.z, (__bf16)y.w };
  *(bf16x4v*)(outb + off) = yb;
}

extern "C" void kernel_launch(void* const* d_in, const int* in_sizes, int n_in,
                              void* d_out, int out_size, void* d_ws, size_t ws_size,
                              hipStream_t stream) {
  (void)in_sizes; (void)n_in; (void)out_size; (void)ws_size;
  const int*   tox  = (const int*)d_in[0];
  const float* emb  = (const float*)d_in[3];
  const float* q_w  = (const float*)d_in[4];
  const float* k_w  = (const float*)d_in[5];
  const float* v_w  = (const float*)d_in[6];
  const float* o_w  = (const float*)d_in[7];
  const float* r_w  = (const float*)d_in[8];
  const float* rwb  = (const float*)d_in[9];
  const float* rrb  = (const float*)d_in[10];
  const float* ln1g = (const float*)d_in[11];
  const float* ln1b = (const float*)d_in[12];
  const float* fw1  = (const float*)d_in[13];
  const float* fb1  = (const float*)d_in[14];
  const float* fw2  = (const float*)d_in[15];
  const float* fb2  = (const float*)d_in[16];
  const float* ln2g = (const float*)d_in[17];
  const float* ln2b = (const float*)d_in[18];
  const float* sumw = (const float*)d_in[19];
  const float* sumb = (const float*)d_in[20];
  const float* pjw  = (const float*)d_in[21];
  const float* pjb  = (const float*)d_in[22];
  float* out = (float*)d_out;

  // ---- workspace bump allocator (256B aligned), ~300 MB total (<= 305 MB proven) ----
  char* wsp = (char*)d_ws;
  auto alloc = [&](size_t bytes) { char* rp = wsp; wsp += (bytes + 255) & ~(size_t)255; return rp; };
  __bf16* qkvw   = (__bf16*)alloc((size_t)LAYERS*2304*768*2);
  __bf16* rwt    = (__bf16*)alloc((size_t)LAYERS*768*768*2);
  __bf16* owb    = (__bf16*)alloc((size_t)LAYERS*768*768*2);
  __bf16* ff1t   = (__bf16*)alloc((size_t)LAYERS*768*3072*2);
  __bf16* ff2t   = (__bf16*)alloc((size_t)LAYERS*3072*768*2);
  float*  h      = (float*) alloc((size_t)NTOK*DMODEL*4);
  __bf16* h_bf   = (__bf16*)alloc((size_t)NTOK*DMODEL*2);
  __bf16* r_bf   = (__bf16*)alloc((size_t)KLEN*DMODEL*2);
  __bf16* krb    = (__bf16*)alloc(((size_t)LAYERS*KLEN + 8)*DMODEL*2);  // +pad rows (window overreach)
  __bf16* vtg    = (__bf16*)alloc((size_t)96*64*512*2);
  __bf16* vec_bf = (__bf16*)alloc((size_t)NTOK*DMODEL*2);
  float*  A5     = (float*) alloc((size_t)3*NTOK*DMODEL*4);   // up to 3 split-K partials, contiguous
  float*  summ   = (float*) alloc((size_t)BATCH*DMODEL*4);
  // union region (25.17 MB): qrw|qrr|kbuf|vb, aliased by mid_bf (dead by FF1 time)
  char*   U      = alloc((size_t)NTOK*DMODEL*2 * 4);
  __bf16* qrw    = (__bf16*)U;
  __bf16* qrr    = (__bf16*)(U + (size_t)NTOK*DMODEL*2);
  __bf16* kbuf   = (__bf16*)(U + (size_t)NTOK*DMODEL*2*2);
  __bf16* vb     = (__bf16*)(U + (size_t)NTOK*DMODEL*2*3);
  __bf16* mid_bf = (__bf16*)U;

  dim3 b256(256);
  // ---- weight convert/transpose ----
  k_wt<<<dim3(24,24,LAYERS), b256, 0, stream>>>(q_w, qkvw, 768, 768, 589824, 2304*768, 0);
  k_wt<<<dim3(24,24,LAYERS), b256, 0, stream>>>(k_w, qkvw, 768, 768, 589824, 2304*768, 768);
  k_wt<<<dim3(24,24,LAYERS), b256, 0, stream>>>(v_w, qkvw, 768, 768, 589824, 2304*768, 1536);
  k_wt<<<dim3(24,24,LAYERS), b256, 0, stream>>>(r_w, rwt, 768, 768, 589824, 589824, 0);
  k_wt<<<dim3(96,24,LAYERS), b256, 0, stream>>>(fw1, ff1t, 3072, 768, (long)768*3072, (long)3072*768, 0);
  k_wt<<<dim3(24,96,LAYERS), b256, 0, stream>>>(fw2, ff2t, 768, 3072, (long)3072*768, (long)768*3072, 0);
  k_cvt<<<(LAYERS*589824/4 + 255)/256, b256, 0, stream>>>(o_w, owb, LAYERS*589824/4);

  k_embed<<<NTOK, b256, 0, stream>>>(tox, emb, h, h_bf);
  k_posenc<<<(KLEN*DMODEL + 255)/256, b256, 0, stream>>>(r_bf);

  // kr for ALL layers in one dispatch: [L][1024][768] bf16
  k_mgemm<0,1,1><<<dim3(6,8,LAYERS), b256, 0, stream>>>(r_bf, rwt, nullptr, krb,
      nullptr, nullptr, nullptr, nullptr, nullptr, nullptr,
      KLEN, 768, 768, (long)589824, (long)KLEN*DMODEL);

  for (int l = 0; l < LAYERS; ++l) {
    // QKV fused (writes qrw/qrr with biases, kbuf, vb)
    k_mgemm<0,2,1><<<dim3(18,32), b256, 0, stream>>>(h_bf, qkvw + (size_t)l*2304*768, nullptr, nullptr,
        qrw, qrr, kbuf, vb, rwb + l*DMODEL, rrb + l*DMODEL, NTOK, 2304, 768, 0, 0);
    // V transpose to [bn][64][512]
    k_vt<<<dim3(16,2,96), b256, 0, stream>>>(vb, vtg);
    // fused attention (AC + BD + softmax + PV)
    k_pv<<<dim3(8,96), b256, 0, stream>>>(qrw, qrr, kbuf, vtg,
        krb + (size_t)l*KLEN*DMODEL, vec_bf);
    // O projection, split-K=2 (384 blocks) -> two f32 partial slabs
    k_mgemm<0,0,2><<<dim3(6,32,2), b256, 0, stream>>>(vec_bf, owb + (size_t)l*589824, nullptr, A5,
        nullptr, nullptr, nullptr, nullptr, nullptr, nullptr, NTOK, 768, 768, 0, (long)NTOK*DMODEL);
    k_ln_res<2><<<NTOK, dim3(192), 0, stream>>>(A5, h, ln1g + l*DMODEL, ln1b + l*DMODEL, h, h_bf);
    // FF
    k_mgemm<1,1,1><<<dim3(24,32), b256, 0, stream>>>(h_bf, ff1t + (size_t)l*768*3072, fb1 + (size_t)l*DFF, mid_bf,
        nullptr, nullptr, nullptr, nullptr, nullptr, nullptr, NTOK, DFF, 768, 0, 0);
    // FF2, split-K=3 (576 blocks) -> three f32 partial slabs
    k_mgemm<0,0,3><<<dim3(6,32,3), b256, 0, stream>>>(mid_bf, ff2t + (size_t)l*3072*768, fb2 + l*DMODEL, A5,
        nullptr, nullptr, nullptr, nullptr, nullptr, nullptr, NTOK, 768, DFF, 0, (long)NTOK*DMODEL);
    k_ln_res<3><<<NTOK, dim3(192), 0, stream>>>(A5, h, ln2g + l*DMODEL, ln2b + l*DMODEL, h, h_bf);
  }

  const float* lastp = h + (size_t)(NTOK - BATCH)*DMODEL;
  k_head1<<<dim3(48), b256, 0, stream>>>(lastp, sumw, sumb, summ);
  k_head2<<<dim3(1), dim3(128), 0, stream>>>(summ, pjw, pjb, out);
}

// Round 7
// 2171.934 us; speedup vs baseline: 13.3982x; 1.0414x over previous
//
#include <hip/hip_runtime.h>
#include <math.h>
#include <stdint.h>

#define LAYERS 12
#define DMODEL 768
#define NHEAD 12
#define DHEAD 64
#define DFF 3072
#define BATCH 8
#define SEQ 512
#define NTOK (BATCH*SEQ)   /* 4096 */
#define KLEN 1024
#define SCALE 0.125f       /* 1/sqrt(64) */

typedef __bf16 bf16x8 __attribute__((ext_vector_type(8)));
typedef __bf16 bf16x4v __attribute__((ext_vector_type(4)));
typedef float f32x4 __attribute__((ext_vector_type(4)));

__device__ __forceinline__ void gld16(const void* g, void* l) {
  auto gp = reinterpret_cast<const __attribute__((address_space(1))) void*>(
      reinterpret_cast<uintptr_t>(g));
  auto lp = reinterpret_cast<__attribute__((address_space(3))) void*>(
      reinterpret_cast<uintptr_t>(l));
  __builtin_amdgcn_global_load_lds(gp, lp, 16, 0, 0);
}

// exact GELU via A&S 7.1.26 erf (|err|<=1.5e-7, cheaper than libm erff)
__device__ __forceinline__ float gelu_exact(float v) {
  float a = v * 0.70710678118654752f;
  float ax = fabsf(a);
  float t = 1.0f / (1.0f + 0.3275911f * ax);
  float y = t*(0.254829592f + t*(-0.284496736f + t*(1.421413741f +
            t*(-1.453152027f + t*1.061405429f))));
  float erf = 1.0f - y * __expf(-ax*ax);
  erf = copysignf(erf, a);
  return 0.5f * v * (1.0f + erf);
}

// ---------------- fused embedding gather + positional encoding ----------------
__global__ void k_init(const int* __restrict__ tox, const float* __restrict__ emb,
                       float* __restrict__ h, __bf16* __restrict__ hb,
                       __bf16* __restrict__ r) {
  int blk = blockIdx.x;
  if (blk < NTOK) {
    int i = blk >> 3, b = blk & 7;
    int tok = tox[b*SEQ + i];
    const float* src = emb + (size_t)tok * DMODEL;
    size_t off = (size_t)blk * DMODEL;
    for (int d = threadIdx.x; d < DMODEL; d += blockDim.x) {
      float v = src[d];
      h[off+d] = v; hb[off+d] = (__bf16)v;
    }
  } else {
    int idx = (blk - NTOK)*256 + threadIdx.x;   // [0, KLEN*DMODEL)
    int k = idx / DMODEL, d = idx % DMODEL;
    float pos = (float)(SEQ - k);
    int j = (d < 384) ? d : d - 384;
    float invf = powf(10000.0f, -(2.0f * (float)j) / 768.0f);
    float a = pos * invf;
    r[idx] = (__bf16)((d < 384) ? sinf(a) : cosf(a));
  }
}

// ---------------- weight transpose+convert: f32 [K][N] -> bf16 [N][K] ----------------
__global__ __launch_bounds__(256) void k_wt(const float* __restrict__ src, __bf16* __restrict__ dst,
                                            int srcN, int dstK, long sstride, long dstride, int drowoff) {
  __shared__ float t[32][33];
  int nt = blockIdx.x, kt = blockIdx.y, l = blockIdx.z;
  const float* s = src + (size_t)l * sstride;
  __bf16* d = dst + (size_t)l * dstride;
  int r = threadIdx.x >> 3, c4 = (threadIdx.x & 7) * 4;
  float4 v = *(const float4*)&s[(size_t)(kt*32 + r)*srcN + nt*32 + c4];
  t[r][c4+0]=v.x; t[r][c4+1]=v.y; t[r][c4+2]=v.z; t[r][c4+3]=v.w;
  __syncthreads();
  bf16x4v o = { (__bf16)t[c4+0][r], (__bf16)t[c4+1][r], (__bf16)t[c4+2][r], (__bf16)t[c4+3][r] };
  *(bf16x4v*)&d[(size_t)(drowoff + nt*32 + r)*dstK + kt*32 + c4] = o;
}

// ---------------- flat convert f32 -> bf16 (x4) ----------------
__global__ void k_cvt(const float* __restrict__ s, __bf16* __restrict__ d, int n4) {
  int i = blockIdx.x*256 + threadIdx.x;
  if (i >= n4) return;
  float4 v = ((const float4*)s)[i];
  bf16x4v o = { (__bf16)v.x, (__bf16)v.y, (__bf16)v.z, (__bf16)v.w };
  ((bf16x4v*)d)[i] = o;
}

// ---------------- V transpose: vb[4096][768] head-cols -> vtg[bn][64][512] ----------------
__global__ __launch_bounds__(256) void k_vt(const __bf16* __restrict__ vb, __bf16* __restrict__ vtg) {
  __shared__ __bf16 t[32][36];
  int it = blockIdx.x, dt = blockIdx.y, bn = blockIdx.z;
  int b = bn / 12, n = bn % 12;
  int r = threadIdx.x >> 3, c4 = (threadIdx.x & 7) * 4;
  bf16x4v v = *(const bf16x4v*)&vb[((size_t)(it*32 + r)*8 + b)*768 + n*64 + dt*32 + c4];
  t[r][c4+0]=v[0]; t[r][c4+1]=v[1]; t[r][c4+2]=v[2]; t[r][c4+3]=v[3];
  __syncthreads();
  bf16x4v o = { t[c4+0][r], t[c4+1][r], t[c4+2][r], t[c4+3][r] };
  *(bf16x4v*)&vtg[((size_t)bn*64 + dt*32 + r)*512 + it*32 + c4] = o;
}

// ---------------- MFMA GEMM (BK=64): C[M,N] = A[M,K] @ B^T, B is [N][K] bf16 ----------------
// ACT: 0 none, 1 exact GELU.  OUTM: 0 f32 (+z*cz), 1 bf16 (+z*cz), 2 QKV split (plain bf16 x3)
// SPLITK: 1 normal (z selects B/C slab), >1: z selects K-slice, partials to z*cz
template<int ACT, int OUTM, int SPLITK>
__global__ __launch_bounds__(256) void k_mgemm(
    const __bf16* __restrict__ A, const __bf16* __restrict__ B,
    const float* __restrict__ bias, void* __restrict__ Cv,
    __bf16* __restrict__ q1, __bf16* __restrict__ kk, __bf16* __restrict__ vv,
    int M, int N, int K, long bz, long cz) {
  __shared__ __align__(16) __bf16 As[128*64];   // 16 KB
  __shared__ __align__(16) __bf16 Bs[128*64];   // 16 KB
  int tid = threadIdx.x;
  int wave = tid >> 6, lane = tid & 63;
  int lr = lane & 15, lc = lane >> 4;
  int wm = wave >> 1, wn = wave & 1;
  int m0 = blockIdx.y * 128, n0 = blockIdx.x * 128;
  const __bf16* Bp = B + (SPLITK > 1 ? 0 : (size_t)blockIdx.z * bz);
  int kbeg = (SPLITK > 1) ? blockIdx.z * (K/SPLITK) : 0;
  int kend = (SPLITK > 1) ? kbeg + K/SPLITK : K;

  f32x4 acc[4][4];
  #pragma unroll
  for (int i = 0; i < 4; ++i)
    #pragma unroll
    for (int j = 0; j < 4; ++j) acc[i][j] = f32x4{0.f,0.f,0.f,0.f};

  int srow[4], scc[4];
  #pragma unroll
  for (int c = 0; c < 4; ++c) {
    int id = c*256 + tid;
    srow[c] = id >> 3;
    scc[c]  = (id & 7) ^ (srow[c] & 7);
  }

  for (int k0 = kbeg; k0 < kend; k0 += 64) {
    __syncthreads();
    #pragma unroll
    for (int c = 0; c < 4; ++c)
      gld16(A + (size_t)(m0 + srow[c])*K + k0 + scc[c]*8,
            (char*)As + c*4096 + wave*1024);
    #pragma unroll
    for (int c = 0; c < 4; ++c)
      gld16(Bp + (size_t)(n0 + srow[c])*K + k0 + scc[c]*8,
            (char*)Bs + c*4096 + wave*1024);
    __syncthreads();
    #pragma unroll
    for (int ks = 0; ks < 2; ++ks) {
      bf16x8 af[4], bfr[4];
      #pragma unroll
      for (int mi = 0; mi < 4; ++mi) {
        int row = wm*64 + mi*16 + lr;
        af[mi] = *(const bf16x8*)((const char*)As + row*128 + (((lc + ks*4) ^ (row & 7))*16));
      }
      #pragma unroll
      for (int ni = 0; ni < 4; ++ni) {
        int row = wn*64 + ni*16 + lr;
        bfr[ni] = *(const bf16x8*)((const char*)Bs + row*128 + (((lc + ks*4) ^ (row & 7))*16));
      }
      #pragma unroll
      for (int mi = 0; mi < 4; ++mi)
        #pragma unroll
        for (int ni = 0; ni < 4; ++ni)
          acc[mi][ni] = __builtin_amdgcn_mfma_f32_16x16x32_bf16(af[mi], bfr[ni], acc[mi][ni], 0, 0, 0);
    }
  }

  #pragma unroll
  for (int mi = 0; mi < 4; ++mi) {
    #pragma unroll
    for (int ni = 0; ni < 4; ++ni) {
      int gn = n0 + wn*64 + ni*16 + lr;
      float bv = (bias && (SPLITK == 1 || blockIdx.z == 0)) ? bias[gn] : 0.f;
      #pragma unroll
      for (int j = 0; j < 4; ++j) {
        int gm = m0 + wm*64 + mi*16 + lc*4 + j;
        float v = acc[mi][ni][j] + bv;
        if (ACT == 1) v = gelu_exact(v);
        if (OUTM == 0) {
          ((float*)Cv)[(size_t)blockIdx.z*cz + (size_t)gm*N + gn] = v;
        } else if (OUTM == 1) {
          ((__bf16*)Cv)[(size_t)blockIdx.z*cz + (size_t)gm*N + gn] = (__bf16)v;
        } else {
          if (gn < 768)       q1[(size_t)gm*768 + gn]        = (__bf16)v;
          else if (gn < 1536) kk[(size_t)gm*768 + gn - 768]  = (__bf16)v;
          else                vv[(size_t)gm*768 + gn - 1536] = (__bf16)v;
        }
      }
    }
  }
}

// ---------------- fused flash attention: AC mfma + BD mfma (rel-shift) + softmax + PV ----------------
// grid (8 itiles of 64, 96 bn), block 256 (4 waves, 16 queries each)
// Q biases (rwb for AC, rrb for BD) are added in-register from the single unbiased qh
__global__ __launch_bounds__(256) void k_pv(
    const __bf16* __restrict__ qh, const __bf16* __restrict__ kb,
    const __bf16* __restrict__ vtg, const __bf16* __restrict__ krb,
    const float* __restrict__ rwb, const float* __restrict__ rrb,
    __bf16* __restrict__ vec) {
  // LDS: KT 8K @0 | VT 8K @8192 | KR 16K @16384 | BD 64x68 bf16 @32768 (8704) | P @41472 (2K/wave)
  __shared__ __align__(16) char lds[49664];
  int tid = threadIdx.x;
  int w = tid >> 6, lane = tid & 63;
  int lr = lane & 15, lg = lane >> 4;
  int bn = blockIdx.y;
  int b = bn / 12, n = bn % 12;
  int i0 = blockIdx.x * 64;
  char* KT = lds;
  char* VT = lds + 8192;
  char* KR = lds + 16384;
  char* BD = lds + 32768;
  char* Plds = lds + 41472 + w*2048;
  int base449 = 449 - i0;          // kr window origin (abs row of rel 0)

  // ---- prestage: qh tile into KT + full 128-row KR window (rel rows [0,128)) ----
  #pragma unroll
  for (int c = 0; c < 2; ++c) {
    int id = c*256 + tid;
    int row = id >> 3, cc = (id & 7) ^ (row & 7);
    gld16(qh + ((size_t)(i0 + row)*8 + b)*768 + n*64 + cc*8, KT + c*4096 + w*1024);
  }
  #pragma unroll
  for (int c = 0; c < 4; ++c) {
    int id = c*256 + tid;
    int row = id >> 3, cc = (id & 7) ^ (row & 7);
    gld16(krb + (size_t)(base449 + row)*768 + n*64 + cc*8, KR + c*4096 + w*1024);
  }
  __syncthreads();
  // Q frags with biases added in fp32 (frag k-chunk = dims (lg+ks*4)*8..+8 per the swizzle algebra)
  bf16x8 qwf[2], qrf[2];
  #pragma unroll
  for (int ks = 0; ks < 2; ++ks) {
    int row = w*16 + lr;
    bf16x8 q0 = *(const bf16x8*)(KT + row*128 + (((lg + ks*4) ^ (row & 7))*16));
    const float* bw = rwb + n*64 + (lg + ks*4)*8;
    const float* br = rrb + n*64 + (lg + ks*4)*8;
    #pragma unroll
    for (int e = 0; e < 8; ++e) {
      float base = (float)q0[e];
      qwf[ks][e] = (__bf16)(base + bw[e]);
      qrf[ks][e] = (__bf16)(base + br[e]);
    }
  }

  f32x4 O[4];
  #pragma unroll
  for (int d = 0; d < 4; ++d) O[d] = f32x4{0.f,0.f,0.f,0.f};
  float m_run = -1e30f, den = 0.f;

  for (int jt = 0; jt < 8; ++jt) {
    int j0 = jt * 64;
    __syncthreads();                    // prev tile consumed (and Q frags read on iter 0)
    // stage K [64][64], Vt [64][64]
    #pragma unroll
    for (int c = 0; c < 2; ++c) {
      int id = c*256 + tid;
      int row = id >> 3, cc = (id & 7) ^ (row & 7);
      gld16(kb + ((size_t)(j0 + row)*8 + b)*768 + n*64 + cc*8, KT + c*4096 + w*1024);
      gld16(vtg + ((size_t)bn*64 + row)*512 + j0 + cc*8, VT + c*4096 + w*1024);
    }
    // stage 64 NEW kr rows (rel [64*jt+64, 64*jt+128)) into ring slots
    if (jt) {
      int sb = (64*(jt+1)) & 127;       // 0 or 64
      #pragma unroll
      for (int c = 0; c < 2; ++c) {
        int id = c*256 + tid;
        int rw = id >> 3;               // 0..63
        int cc = (id & 7) ^ (rw & 7);   // slot&7 == rw&7 (sb multiple of 64)
        gld16(krb + (size_t)(base449 + 64*jt + 64 + rw)*768 + n*64 + cc*8,
              KR + sb*128 + c*4096 + w*1024);
      }
    }
    __syncthreads();

    __builtin_amdgcn_s_setprio(1);
    // ---- AC: mfma(K, Qw): lane holds q = lr, keys = ksub*16 + lg*4 + r ----
    f32x4 acf[4];
    #pragma unroll
    for (int ksub = 0; ksub < 4; ++ksub) acf[ksub] = f32x4{0.f,0.f,0.f,0.f};
    #pragma unroll
    for (int ks = 0; ks < 2; ++ks) {
      #pragma unroll
      for (int ksub = 0; ksub < 4; ++ksub) {
        int row = ksub*16 + lr;
        bf16x8 kf = *(const bf16x8*)(KT + row*128 + (((lg + ks*4) ^ (row & 7))*16));
        acf[ksub] = __builtin_amdgcn_mfma_f32_16x16x32_bf16(kf, qwf[ks], acf[ksub], 0, 0, 0);
      }
    }
    // ---- BD: mfma(Qr, KRwin). Only kt in [3-w, 7-w] yields in-band jloc for wave w ----
    int ktbase = 3 - w;
    #pragma unroll
    for (int t = 0; t < 5; ++t) {
      int kt = ktbase + t;
      f32x4 bda = f32x4{0.f,0.f,0.f,0.f};
      #pragma unroll
      for (int ks = 0; ks < 2; ++ks) {
        int rowk = kt*16 + lr;
        int s = (64*jt + rowk) & 127;   // ring slot; s&7 == rowk&7
        bf16x8 krf = *(const bf16x8*)(KR + s*128 + (((lg + ks*4) ^ (rowk & 7))*16));
        bda = __builtin_amdgcn_mfma_f32_16x16x32_bf16(qrf[ks], krf, bda, 0, 0, 0);
      }
      #pragma unroll
      for (int jreg = 0; jreg < 4; ++jreg) {
        int il = w*16 + lg*4 + jreg;              // i_local in [0,64)
        int jloc = kt*16 + lr + il - 63;
        if ((unsigned)jloc < 64u)
          *(__bf16*)(BD + (il*68 + jloc)*2) = (__bf16)bda[jreg];
      }
    }
    __builtin_amdgcn_s_setprio(0);

    // ---- softmax (lane owns query q = lr of wave w) ----
    float sc[4][4];
    float mt = -1e30f;
    int qrow = w*16 + lr;
    #pragma unroll
    for (int ksub = 0; ksub < 4; ++ksub) {
      bf16x4v bdv = *(const bf16x4v*)(BD + (qrow*68 + ksub*16 + lg*4)*2);
      #pragma unroll
      for (int r = 0; r < 4; ++r) {
        float s = (acf[ksub][r] + (float)bdv[r]) * SCALE;
        sc[ksub][r] = s;
        mt = fmaxf(mt, s);
      }
    }
    mt = fmaxf(mt, __shfl_xor(mt, 16));
    mt = fmaxf(mt, __shfl_xor(mt, 32));
    float m_new = fmaxf(m_run, mt);
    float f = __expf(m_run - m_new);
    m_run = m_new;
    float psum = 0.f;
    #pragma unroll
    for (int ksub = 0; ksub < 4; ++ksub) {
      bf16x4v pv;
      #pragma unroll
      for (int r = 0; r < 4; ++r) {
        float p = __expf(sc[ksub][r] - m_new);
        psum += p;
        pv[r] = (__bf16)p;
      }
      int k = ksub*16 + lg*4;
      *(bf16x4v*)(Plds + lr*128 + (((k >> 3) ^ (lr & 7))*16) + (k & 7)*2) = pv;
    }
    den = den*f + psum;
    float fv[4];
    #pragma unroll
    for (int j = 0; j < 4; ++j) fv[j] = __shfl(f, lg*4 + j);
    #pragma unroll
    for (int d = 0; d < 4; ++d)
      #pragma unroll
      for (int j = 0; j < 4; ++j) O[d][j] *= fv[j];
    // ---- PV: mfma(P, Vt): D[row=q][col=d] ----
    __builtin_amdgcn_s_setprio(1);
    #pragma unroll
    for (int ks = 0; ks < 2; ++ks) {
      bf16x8 paf = *(const bf16x8*)(Plds + lr*128 + (((lg + ks*4) ^ (lr & 7))*16));
      #pragma unroll
      for (int d = 0; d < 4; ++d) {
        int row = d*16 + lr;
        bf16x8 vf = *(const bf16x8*)(VT + row*128 + (((lg + ks*4) ^ (row & 7))*16));
        O[d] = __builtin_amdgcn_mfma_f32_16x16x32_bf16(paf, vf, O[d], 0, 0, 0);
      }
    }
    __builtin_amdgcn_s_setprio(0);
  }

  den += __shfl_xor(den, 16);
  den += __shfl_xor(den, 32);
  float inv = 1.0f / den;
  float iv[4];
  #pragma unroll
  for (int j = 0; j < 4; ++j) iv[j] = __shfl(inv, lg*4 + j);
  #pragma unroll
  for (int d = 0; d < 4; ++d) {
    #pragma unroll
    for (int j = 0; j < 4; ++j) {
      int qg = i0 + w*16 + lg*4 + j;
      int dd = d*16 + lr;
      vec[((size_t)qg*8 + b)*768 + n*64 + dd] = (__bf16)(O[d][j] * iv[j]);
    }
  }
}

// ---------------- head: summ = tanh(last[8][768] @ sumw + sumb) ----------------
__global__ __launch_bounds__(256) void k_head1(
    const float* __restrict__ last, const float* __restrict__ sumw,
    const float* __restrict__ sumb, float* __restrict__ summ) {
  __shared__ float red[256];
  int tid = threadIdx.x;
  int nn = blockIdx.x*16 + (tid & 15);
  int r = (tid >> 4) & 7;
  int half = tid >> 7;
  const float4* lp4 = (const float4*)(last + (size_t)r*768 + half*384);
  const float* wp = sumw + (size_t)half*384*768 + nn;
  float s = 0.f;
  #pragma unroll 2
  for (int k4 = 0; k4 < 96; ++k4) {
    float4 u = lp4[k4];
    const float* w0 = wp + (size_t)k4*4*768;
    s += u.x*w0[0] + u.y*w0[768] + u.z*w0[1536] + u.w*w0[2304];
  }
  red[tid] = s;
  __syncthreads();
  if (tid < 128) {
    float t = red[tid] + red[tid + 128];
    summ[(size_t)r*768 + nn] = tanhf(t + sumb[nn]);
  }
}

// ---------------- head: out = summ[8][768] @ pjw[768][2] + pjb ----------------
__global__ __launch_bounds__(128) void k_head2(
    const float* __restrict__ summ, const float* __restrict__ pjw,
    const float* __restrict__ pjb, float* __restrict__ out) {
  __shared__ float red[128];
  int tid = threadIdx.x;
  int o = tid & 15;
  int r = o >> 1, c = o & 1;
  int seg = tid >> 4;
  float s = 0.f;
  #pragma unroll 4
  for (int k = seg*96; k < seg*96 + 96; ++k) s += summ[(size_t)r*768 + k] * pjw[(size_t)k*2 + c];
  red[tid] = s;
  __syncthreads();
  if (tid < 16) {
    float t = 0.f;
    #pragma unroll
    for (int sg = 0; sg < 8; ++sg) t += red[sg*16 + tid];
    out[tid] = t + pjb[tid & 1];
  }
}

// ---------------- LayerNorm(sum of PARTS slabs + res) -> out fp32 + bf16 ----------------
template<int PARTS>
__global__ __launch_bounds__(192) void k_ln_res(
    const float* __restrict__ x, const float* __restrict__ res,
    const float* __restrict__ g, const float* __restrict__ bta,
    float* __restrict__ out, __bf16* __restrict__ outb) {
  __shared__ float red[6];
  int row = blockIdx.x, tid = threadIdx.x;
  size_t off = (size_t)row*768 + tid*4;
  float4 v = *(const float4*)(x + off);
  #pragma unroll
  for (int p = 1; p < PARTS; ++p) {
    float4 u = *(const float4*)(x + (size_t)p*NTOK*DMODEL + off);
    v.x += u.x; v.y += u.y; v.z += u.z; v.w += u.w;
  }
  {
    float4 u = *(const float4*)(res + off);
    v.x += u.x; v.y += u.y; v.z += u.z; v.w += u.w;
  }
  float s = v.x + v.y + v.z + v.w;
  #pragma unroll
  for (int o = 32; o; o >>= 1) s += __shfl_down(s, o, 64);
  if ((tid & 63) == 0) red[tid >> 6] = s;
  __syncthreads();
  float mean = (red[0] + red[1] + red[2]) * (1.0f/768.0f);
  float a0 = v.x - mean, a1 = v.y - mean, a2 = v.z - mean, a3 = v.w - mean;
  float vs = a0*a0 + a1*a1 + a2*a2 + a3*a3;
  #pragma unroll
  for (int o = 32; o; o >>= 1) vs += __shfl_down(vs, o, 64);
  if ((tid & 63) == 0) red[3 + (tid >> 6)] = vs;
  __syncthreads();
  float var = (red[3] + red[4] + red[5]) * (1.0f/768.0f);
  float rstd = 1.0f / sqrtf(var + 1e-12f);
  float4 gv = *(const float4*)(g + tid*4);
  float4 bv = *(const float4*)(bta + tid*4);
  float4 y;
  y.x = a0*rstd*gv.x + bv.x;
  y.y = a1*rstd*gv.y + bv.y;
  y.z = a2*rstd*gv.z + bv.z;
  y.w = a3*rstd*gv.w + bv.w;
  *(float4*)(out + off) = y;
  bf16x4v yb = { (__bf16)y.x, (__bf16)y.y, (__bf16)y.z, (__bf16)y.w };
  *(bf16x4v*)(outb + off) = yb;
}

extern "C" void kernel_launch(void* const* d_in, const int* in_sizes, int n_in,
                              void* d_out, int out_size, void* d_ws, size_t ws_size,
                              hipStream_t stream) {
  (void)in_sizes; (void)n_in; (void)out_size; (void)ws_size;
  const int*   tox  = (const int*)d_in[0];
  const float* emb  = (const float*)d_in[3];
  const float* q_w  = (const float*)d_in[4];
  const float* k_w  = (const float*)d_in[5];
  const float* v_w  = (const float*)d_in[6];
  const float* o_w  = (const float*)d_in[7];
  const float* r_w  = (const float*)d_in[8];
  const float* rwb  = (const float*)d_in[9];
  const float* rrb  = (const float*)d_in[10];
  const float* ln1g = (const float*)d_in[11];
  const float* ln1b = (const float*)d_in[12];
  const float* fw1  = (const float*)d_in[13];
  const float* fb1  = (const float*)d_in[14];
  const float* fw2  = (const float*)d_in[15];
  const float* fb2  = (const float*)d_in[16];
  const float* ln2g = (const float*)d_in[17];
  const float* ln2b = (const float*)d_in[18];
  const float* sumw = (const float*)d_in[19];
  const float* sumb = (const float*)d_in[20];
  const float* pjw  = (const float*)d_in[21];
  const float* pjb  = (const float*)d_in[22];
  float* out = (float*)d_out;

  // ---- workspace bump allocator (256B aligned), ~289 MB total ----
  char* wsp = (char*)d_ws;
  auto alloc = [&](size_t bytes) { char* rp = wsp; wsp += (bytes + 255) & ~(size_t)255; return rp; };
  __bf16* qkvw   = (__bf16*)alloc((size_t)LAYERS*2304*768*2);
  __bf16* rwt    = (__bf16*)alloc((size_t)LAYERS*768*768*2);
  __bf16* owb    = (__bf16*)alloc((size_t)LAYERS*768*768*2);
  __bf16* ff1t   = (__bf16*)alloc((size_t)LAYERS*768*3072*2);
  __bf16* ff2t   = (__bf16*)alloc((size_t)LAYERS*3072*768*2);
  float*  h      = (float*) alloc((size_t)NTOK*DMODEL*4);
  __bf16* h_bf   = (__bf16*)alloc((size_t)NTOK*DMODEL*2);
  __bf16* r_bf   = (__bf16*)alloc((size_t)KLEN*DMODEL*2);
  __bf16* krb    = (__bf16*)alloc(((size_t)LAYERS*KLEN + 8)*DMODEL*2);  // +pad rows (window overreach)
  __bf16* vec_bf = (__bf16*)alloc((size_t)NTOK*DMODEL*2);
  float*  A5     = (float*) alloc((size_t)3*NTOK*DMODEL*4);   // up to 3 split-K partials, contiguous
  float*  summ   = (float*) alloc((size_t)BATCH*DMODEL*4);
  // union region (25.17 MB): [qh | kbuf | vb | vtg], aliased by mid_bf (all dead by FF1 time)
  char*   U      = alloc((size_t)NTOK*DMODEL*2 * 4);
  __bf16* qh     = (__bf16*)U;
  __bf16* kbuf   = (__bf16*)(U + (size_t)NTOK*DMODEL*2);
  __bf16* vb     = (__bf16*)(U + (size_t)NTOK*DMODEL*2*2);
  __bf16* vtg    = (__bf16*)(U + (size_t)NTOK*DMODEL*2*3);
  __bf16* mid_bf = (__bf16*)U;

  dim3 b256(256);
  // ---- weight convert/transpose ----
  k_wt<<<dim3(24,24,LAYERS), b256, 0, stream>>>(q_w, qkvw, 768, 768, 589824, 2304*768, 0);
  k_wt<<<dim3(24,24,LAYERS), b256, 0, stream>>>(k_w, qkvw, 768, 768, 589824, 2304*768, 768);
  k_wt<<<dim3(24,24,LAYERS), b256, 0, stream>>>(v_w, qkvw, 768, 768, 589824, 2304*768, 1536);
  k_wt<<<dim3(24,24,LAYERS), b256, 0, stream>>>(r_w, rwt, 768, 768, 589824, 589824, 0);
  k_wt<<<dim3(96,24,LAYERS), b256, 0, stream>>>(fw1, ff1t, 3072, 768, (long)768*3072, (long)3072*768, 0);
  k_wt<<<dim3(24,96,LAYERS), b256, 0, stream>>>(fw2, ff2t, 768, 3072, (long)3072*768, (long)768*3072, 0);
  k_cvt<<<(LAYERS*589824/4 + 255)/256, b256, 0, stream>>>(o_w, owb, LAYERS*589824/4);

  // embed + posenc fused (4096 + 3072 blocks)
  k_init<<<NTOK + KLEN*DMODEL/256, b256, 0, stream>>>(tox, emb, h, h_bf, r_bf);

  // kr for ALL layers in one dispatch: [L][1024][768] bf16
  k_mgemm<0,1,1><<<dim3(6,8,LAYERS), b256, 0, stream>>>(r_bf, rwt, nullptr, krb,
      nullptr, nullptr, nullptr, KLEN, 768, 768, (long)589824, (long)KLEN*DMODEL);

  for (int l = 0; l < LAYERS; ++l) {
    // QKV fused (writes unbiased qh, kbuf, vb)
    k_mgemm<0,2,1><<<dim3(18,32), b256, 0, stream>>>(h_bf, qkvw + (size_t)l*2304*768, nullptr, nullptr,
        qh, kbuf, vb, NTOK, 2304, 768, 0, 0);
    // V transpose to [bn][64][512]
    k_vt<<<dim3(16,2,96), b256, 0, stream>>>(vb, vtg);
    // fused attention (AC + BD + softmax + PV); Q biases added in-register
    k_pv<<<dim3(8,96), b256, 0, stream>>>(qh, kbuf, vtg, krb + (size_t)l*KLEN*DMODEL,
        rwb + l*DMODEL, rrb + l*DMODEL, vec_bf);
    // O projection, split-K=2 (384 blocks) -> two f32 partial slabs
    k_mgemm<0,0,2><<<dim3(6,32,2), b256, 0, stream>>>(vec_bf, owb + (size_t)l*589824, nullptr, A5,
        nullptr, nullptr, nullptr, NTOK, 768, 768, 0, (long)NTOK*DMODEL);
    k_ln_res<2><<<NTOK, dim3(192), 0, stream>>>(A5, h, ln1g + l*DMODEL, ln1b + l*DMODEL, h, h_bf);
    // FF
    k_mgemm<1,1,1><<<dim3(24,32), b256, 0, stream>>>(h_bf, ff1t + (size_t)l*768*3072, fb1 + (size_t)l*DFF, mid_bf,
        nullptr, nullptr, nullptr, NTOK, DFF, 768, 0, 0);
    // FF2, split-K=3 (576 blocks) -> three f32 partial slabs
    k_mgemm<0,0,3><<<dim3(6,32,3), b256, 0, stream>>>(mid_bf, ff2t + (size_t)l*3072*768, fb2 + l*DMODEL, A5,
        nullptr, nullptr, nullptr, NTOK, 768, DFF, 0, (long)NTOK*DMODEL);
    k_ln_res<3><<<NTOK, dim3(192), 0, stream>>>(A5, h, ln2g + l*DMODEL, ln2b + l*DMODEL, h, h_bf);
  }

  const float* lastp = h + (size_t)(NTOK - BATCH)*DMODEL;
  k_head1<<<dim3(48), b256, 0, stream>>>(lastp, sumw, sumb, summ);
  k_head2<<<dim3(1), dim3(128), 0, stream>>>(summ, pjw, pjb, out);
}